// Round 1
// baseline (804.901 us; speedup 1.0000x reference)
//
#include <hip/hip_runtime.h>

#define EPS 1e-6f

typedef float f32x4 __attribute__((ext_vector_type(4)));
typedef short bf16x8 __attribute__((ext_vector_type(8)));

__device__ __forceinline__ unsigned short f2bf(float f) {
  unsigned int u = __float_as_uint(f);
  u = u + 0x7fffu + ((u >> 16) & 1u);  // round-to-nearest-even
  return (unsigned short)(u >> 16);
}
__device__ __forceinline__ float bf2f(unsigned short h) {
  return __uint_as_float(((unsigned int)h) << 16);
}

// ---------------- fp32 GEMM: C[M,N] = A[M,K] @ B[K,N] ----------------
// M,N multiples of 128; K multiple of 16. 256 threads, 8x8 per thread.
__global__ __launch_bounds__(256) void gemm_f32_kernel(
    const float* __restrict__ A, const float* __restrict__ B,
    float* __restrict__ C, int M, int N, int K) {
  __shared__ float As[16][132];  // transposed A tile: As[k][m], pad 132 (2-way banks)
  __shared__ float Bs[16][128];

  const int tid = threadIdx.x;
  const int tx = tid & 15, ty = tid >> 4;
  const int bn = blockIdx.x * 128, bm = blockIdx.y * 128;

  float acc[8][8];
#pragma unroll
  for (int i = 0; i < 8; i++)
#pragma unroll
    for (int j = 0; j < 8; j++) acc[i][j] = 0.f;

  const int a_row = tid >> 2;         // 0..63
  const int a_col = (tid & 3) << 2;   // 0,4,8,12
  const int b_row = tid >> 5;         // 0..7
  const int b_col = (tid & 31) << 2;  // 0..124

  for (int k0 = 0; k0 < K; k0 += 16) {
    const float4 av0 = *(const float4*)&A[(bm + a_row) * K + k0 + a_col];
    const float4 av1 = *(const float4*)&A[(bm + a_row + 64) * K + k0 + a_col];
    const float4 bv0 = *(const float4*)&B[(k0 + b_row) * N + bn + b_col];
    const float4 bv1 = *(const float4*)&B[(k0 + b_row + 8) * N + bn + b_col];
    __syncthreads();  // previous iteration's LDS reads complete
    As[a_col + 0][a_row] = av0.x;
    As[a_col + 1][a_row] = av0.y;
    As[a_col + 2][a_row] = av0.z;
    As[a_col + 3][a_row] = av0.w;
    As[a_col + 0][a_row + 64] = av1.x;
    As[a_col + 1][a_row + 64] = av1.y;
    As[a_col + 2][a_row + 64] = av1.z;
    As[a_col + 3][a_row + 64] = av1.w;
    *(float4*)&Bs[b_row][b_col] = bv0;
    *(float4*)&Bs[b_row + 8][b_col] = bv1;
    __syncthreads();
#pragma unroll
    for (int kk = 0; kk < 16; kk++) {
      const float4 a0 = *(const float4*)&As[kk][ty << 2];
      const float4 a1 = *(const float4*)&As[kk][64 + (ty << 2)];
      const float4 b0 = *(const float4*)&Bs[kk][tx << 2];
      const float4 b1 = *(const float4*)&Bs[kk][64 + (tx << 2)];
      const float av[8] = {a0.x, a0.y, a0.z, a0.w, a1.x, a1.y, a1.z, a1.w};
      const float bv[8] = {b0.x, b0.y, b0.z, b0.w, b1.x, b1.y, b1.z, b1.w};
#pragma unroll
      for (int i = 0; i < 8; i++)
#pragma unroll
        for (int j = 0; j < 8; j++) acc[i][j] += av[i] * bv[j];
    }
  }

#pragma unroll
  for (int i = 0; i < 8; i++) {
    const int row = bm + ((i < 4) ? ((ty << 2) + i) : (64 + (ty << 2) + (i - 4)));
    const float4 o0 = {acc[i][0], acc[i][1], acc[i][2], acc[i][3]};
    const float4 o1 = {acc[i][4], acc[i][5], acc[i][6], acc[i][7]};
    *(float4*)&C[row * N + bn + (tx << 2)] = o0;
    *(float4*)&C[row * N + bn + 64 + (tx << 2)] = o1;
  }
}

// ---------------- global sum-of-squares of q and k ----------------
// qkv: 4096 rows x 3072 cols; q = cols [0,1024), k = cols [1024,2048)
__global__ __launch_bounds__(256) void sumsq_kernel(const float* __restrict__ qkv,
                                                    float* __restrict__ sums) {
  float sq = 0.f, sk = 0.f;
  const int nthreads = gridDim.x * blockDim.x;
  for (int idx = blockIdx.x * blockDim.x + threadIdx.x; idx < 4096 * 256;
       idx += nthreads) {
    const int row = idx >> 8;
    const int c = (idx & 255) << 2;
    const float4 q4 = *(const float4*)&qkv[row * 3072 + c];
    const float4 k4 = *(const float4*)&qkv[row * 3072 + 1024 + c];
    sq += q4.x * q4.x + q4.y * q4.y + q4.z * q4.z + q4.w * q4.w;
    sk += k4.x * k4.x + k4.y * k4.y + k4.z * k4.z + k4.w * k4.w;
  }
#pragma unroll
  for (int off = 32; off > 0; off >>= 1) {
    sq += __shfl_down(sq, off, 64);
    sk += __shfl_down(sk, off, 64);
  }
  __shared__ float blk[8];
  const int lane = threadIdx.x & 63, w = threadIdx.x >> 6;
  if (lane == 0) {
    blk[w] = sq;
    blk[4 + w] = sk;
  }
  __syncthreads();
  if (threadIdx.x == 0) {
    atomicAdd(&sums[0], blk[0] + blk[1] + blk[2] + blk[3]);
    atomicAdd(&sums[1], blk[4] + blk[5] + blk[6] + blk[7]);
  }
}

// ---------------- fused attention ----------------
// One block per (b, h, 16-row q tile). 256 threads = 4 waves.
// QK^T: split-bf16 (hi+lo) MFMA 16x16x32 -> fp32 logits, exp(l - 60) -> bf16 p.
// PV:   bf16 MFMA, v cast on the fly; normalize by fp32 row sums at the end.
__global__ __launch_bounds__(256) void attn_kernel(
    const float* __restrict__ qkv, const float* __restrict__ sums,
    const float* __restrict__ scale_q, const float* __restrict__ scale_k,
    float* __restrict__ z) {
  __shared__ unsigned short qs_h[16][72], qs_l[16][72];  // pad +8 bf16 -> 2-way banks
  __shared__ unsigned short ks_h[64][72], ks_l[64][72];
  __shared__ unsigned short pb[16][1032];                // p (unnormalized), bf16
  __shared__ float red[16][17];
  __shared__ float rowsum[16];

  const int tid = threadIdx.x;
  const int lane = tid & 63;
  const int wv = tid >> 6;     // wave id 0..3
  const int quad = lane >> 4;  // 0..3
  const int lm = lane & 15;
  const int b = blockIdx.z, h = blockIdx.y, qt = blockIdx.x;

  const float inv_rq = 1.f / (sqrtf(sums[0] * (1.f / 4194304.f)) + EPS);
  const float inv_rk = 1.f / (sqrtf(sums[1] * (1.f / 4194304.f)) + EPS);

  // ---- stage normalized q tile (16 x 64), split hi/lo ----
  {
    const int r = tid >> 4;
    const int c = (tid & 15) << 2;
    const float4 v4 = *(const float4*)&qkv[(b * 1024 + qt * 16 + r) * 3072 + h * 64 + c];
    const float fv[4] = {v4.x, v4.y, v4.z, v4.w};
#pragma unroll
    for (int j = 0; j < 4; j++) {
      const float f = fv[j] * inv_rq * scale_q[c + j];
      const unsigned short hi = f2bf(f);
      qs_h[r][c + j] = hi;
      qs_l[r][c + j] = f2bf(f - bf2f(hi));
    }
  }
  __syncthreads();

  // q fragments are loop-invariant: A[m = lane&15][k = quad*8 + j]
  const bf16x8 aH0 = *(const bf16x8*)&qs_h[lm][quad * 8];
  const bf16x8 aH1 = *(const bf16x8*)&qs_h[lm][32 + quad * 8];
  const bf16x8 aL0 = *(const bf16x8*)&qs_l[lm][quad * 8];
  const bf16x8 aL1 = *(const bf16x8*)&qs_l[lm][32 + quad * 8];

  for (int it = 0; it < 16; it++) {
    __syncthreads();  // previous iteration's ks reads complete
    {  // stage 64 normalized k rows, split hi/lo
      const int r = tid >> 2;
      const int cc = (tid & 3) << 4;
      const float* src = &qkv[(b * 1024 + it * 64 + r) * 3072 + 1024 + h * 64 + cc];
#pragma unroll
      for (int u = 0; u < 4; u++) {
        const float4 v4 = *(const float4*)&src[u << 2];
        const float fv[4] = {v4.x, v4.y, v4.z, v4.w};
#pragma unroll
        for (int j = 0; j < 4; j++) {
          const int c = cc + (u << 2) + j;
          const float f = fv[j] * inv_rk * scale_k[c];
          const unsigned short hi = f2bf(f);
          ks_h[r][c] = hi;
          ks_l[r][c] = f2bf(f - bf2f(hi));
        }
      }
    }
    __syncthreads();
    // wave wv computes scores vs k rows [wv*16, wv*16+16)
    const int kr = wv * 16 + lm;
    const bf16x8 bH0 = *(const bf16x8*)&ks_h[kr][quad * 8];
    const bf16x8 bH1 = *(const bf16x8*)&ks_h[kr][32 + quad * 8];
    const bf16x8 bL0 = *(const bf16x8*)&ks_l[kr][quad * 8];
    const bf16x8 bL1 = *(const bf16x8*)&ks_l[kr][32 + quad * 8];
    f32x4 c4 = {0.f, 0.f, 0.f, 0.f};
    c4 = __builtin_amdgcn_mfma_f32_16x16x32_bf16(aH0, bH0, c4, 0, 0, 0);
    c4 = __builtin_amdgcn_mfma_f32_16x16x32_bf16(aH1, bH1, c4, 0, 0, 0);
    c4 = __builtin_amdgcn_mfma_f32_16x16x32_bf16(aL0, bH0, c4, 0, 0, 0);
    c4 = __builtin_amdgcn_mfma_f32_16x16x32_bf16(aL1, bH1, c4, 0, 0, 0);
    c4 = __builtin_amdgcn_mfma_f32_16x16x32_bf16(aH0, bL0, c4, 0, 0, 0);
    c4 = __builtin_amdgcn_mfma_f32_16x16x32_bf16(aH1, bL1, c4, 0, 0, 0);
    // C/D layout: col = lane&15 (k index), row = quad*4 + i (q row)
#pragma unroll
    for (int i = 0; i < 4; i++) {
      const float p = __expf(c4[i] - 60.f);  // softmax shift-invariant; no overflow
      pb[quad * 4 + i][it * 64 + wv * 16 + lm] = f2bf(p);
    }
  }
  __syncthreads();

  // ---- fp32 row sums of unnormalized p ----
  {
    const int r = tid >> 4;
    const int c0 = tid & 15;
    float s = 0.f;
#pragma unroll 8
    for (int j = 0; j < 64; j++) s += bf2f(pb[r][c0 + (j << 4)]);
    red[r][c0] = s;
  }
  __syncthreads();
  if (tid < 16) {
    float s = 0.f;
#pragma unroll
    for (int j = 0; j < 16; j++) s += red[tid][j];
    rowsum[tid] = s;
  }
  __syncthreads();

  // ---- PV: z(16x64), wave wv owns v cols [wv*16, wv*16+16) ----
  f32x4 zacc = {0.f, 0.f, 0.f, 0.f};
  const float* vcol = &qkv[b * 1024 * 3072 + 2048 + h * 64 + wv * 16 + lm];
  for (int kc = 0; kc < 32; kc++) {
    const bf16x8 afr = *(const bf16x8*)&pb[lm][kc * 32 + quad * 8];
    bf16x8 bfr;
#pragma unroll
    for (int j = 0; j < 8; j++) {
      const float vv = vcol[(kc * 32 + quad * 8 + j) * 3072];
      bfr[j] = (short)f2bf(vv);
    }
    zacc = __builtin_amdgcn_mfma_f32_16x16x32_bf16(afr, bfr, zacc, 0, 0, 0);
  }
#pragma unroll
  for (int i = 0; i < 4; i++) {
    const int row = quad * 4 + i;
    z[(b * 1024 + qt * 16 + row) * 1024 + h * 64 + wv * 16 + lm] =
        zacc[i] / rowsum[row];
  }
}

extern "C" void kernel_launch(void* const* d_in, const int* in_sizes, int n_in,
                              void* d_out, int out_size, void* d_ws, size_t ws_size,
                              hipStream_t stream) {
  (void)in_sizes; (void)n_in; (void)out_size; (void)ws_size;
  const float* x = (const float*)d_in[0];
  const float* Wqkv = (const float*)d_in[1];
  const float* Wo = (const float*)d_in[2];
  const float* scale_q = (const float*)d_in[3];
  const float* scale_k = (const float*)d_in[4];
  float* out = (float*)d_out;

  // workspace layout: qkv (4096x3072 f32, 50.3MB) | z (4096x1024 f32, 16.8MB) | sums (2 f32)
  float* qkv = (float*)d_ws;
  float* zbuf = qkv + (size_t)4096 * 3072;
  float* sums = zbuf + (size_t)4096 * 1024;

  // 1) qkv = x @ Wqkv  (fp32 — q/k precision feeds softmax logits)
  gemm_f32_kernel<<<dim3(24, 32), 256, 0, stream>>>(x, Wqkv, qkv, 4096, 3072, 1024);
  // 2) global sum of squares for scalar RMS of q and k
  hipMemsetAsync(sums, 0, 2 * sizeof(float), stream);
  sumsq_kernel<<<dim3(1024), 256, 0, stream>>>(qkv, sums);
  // 3) fused normalize + attention -> z
  attn_kernel<<<dim3(64, 16, 4), 256, 0, stream>>>(qkv, sums, scale_q, scale_k, zbuf);
  // 4) out = z @ Wo (fp32)
  gemm_f32_kernel<<<dim3(8, 32), 256, 0, stream>>>(zbuf, Wo, out, 4096, 1024, 1024);
}

// Round 2
// 290.872 us; speedup vs baseline: 2.7672x; 2.7672x over previous
//
#include <hip/hip_runtime.h>

typedef float f32x4 __attribute__((ext_vector_type(4)));
typedef short bf16x8 __attribute__((ext_vector_type(8)));
typedef unsigned short u16;

__device__ __forceinline__ u16 f2bf(float f) {
  unsigned int u = __float_as_uint(f);
  u = u + 0x7fffu + ((u >> 16) & 1u);  // round-to-nearest-even
  return (u16)(u >> 16);
}
__device__ __forceinline__ float bf2f(u16 h) {
  return __uint_as_float(((unsigned int)h) << 16);
}

typedef unsigned int as1_uint __attribute__((address_space(1)));
typedef unsigned int as3_uint __attribute__((address_space(3)));
// async global->LDS, 16B per lane; LDS dest = base + lane*16 (wave-uniform base)
__device__ __forceinline__ void gl_lds16(const void* g, void* l) {
  __builtin_amdgcn_global_load_lds((as1_uint*)g, (as3_uint*)l, 16, 0, 0);
}

// ============ shared MFMA GEMM core ============
// C(128x128) at (bm,bn), operands K-major with row stride 1024 elements,
// one K-segment of 1024. acc[4][4] per wave (waves 2x2 of 64x64).
__device__ __forceinline__ void gemm_core_seg(
    const u16* __restrict__ Ab, const u16* __restrict__ Bb, int bm, int bn,
    u16* As, u16* Bs, f32x4 acc[4][4], int tid) {
  const int wv = tid >> 6, lane = tid & 63;
  const int lm = lane & 15, quad = lane >> 4;
  const int wr = (wv >> 1) * 64, wc = (wv & 1) * 64;
  const int arow = lane >> 2;          // 4 lanes per 64B row
  const int acol = (lane & 3) * 8;     // 8 bf16 = 16B per lane
  for (int k0 = 0; k0 < 1024; k0 += 32) {
    __syncthreads();  // previous compute done with LDS
#pragma unroll
    for (int j = 0; j < 2; j++) {
      const int r = wv * 32 + j * 16;
      gl_lds16(Ab + (size_t)(bm + r + arow) * 1024 + k0 + acol, As + r * 32);
      gl_lds16(Bb + (size_t)(bn + r + arow) * 1024 + k0 + acol, Bs + r * 32);
    }
    __syncthreads();  // loads landed (vmcnt drained at barrier)
    bf16x8 af[4], bfr[4];
#pragma unroll
    for (int mi = 0; mi < 4; mi++)
      af[mi] = *(const bf16x8*)&As[(wr + mi * 16 + lm) * 32 + quad * 8];
#pragma unroll
    for (int ni = 0; ni < 4; ni++)
      bfr[ni] = *(const bf16x8*)&Bs[(wc + ni * 16 + lm) * 32 + quad * 8];
#pragma unroll
    for (int mi = 0; mi < 4; mi++)
#pragma unroll
      for (int ni = 0; ni < 4; ni++)
        acc[mi][ni] = __builtin_amdgcn_mfma_f32_16x16x32_bf16(
            af[mi], bfr[ni], acc[mi][ni], 0, 0, 0);
  }
}

// ============ converts ============
__global__ __launch_bounds__(256) void conv_x_kernel(
    const float* __restrict__ x, u16* __restrict__ Ah, u16* __restrict__ Al) {
  const int idx = blockIdx.x * 256 + threadIdx.x;  // 4 elems per thread
  const float4 v = ((const float4*)x)[idx];
  ushort4 h, l;
  h.x = f2bf(v.x); l.x = f2bf(v.x - bf2f(h.x));
  h.y = f2bf(v.y); l.y = f2bf(v.y - bf2f(h.y));
  h.z = f2bf(v.z); l.z = f2bf(v.z - bf2f(h.z));
  h.w = f2bf(v.w); l.w = f2bf(v.w - bf2f(h.w));
  ((ushort4*)Ah)[idx] = h;
  ((ushort4*)Al)[idx] = l;
}

// transpose-convert: dstHi[n][k] = hi(src[k][n]); lo written for n < lo_n.
// src is [1024][ncols] f32; 64x64 tiles.
__global__ __launch_bounds__(256) void conv_wT_kernel(
    const float* __restrict__ src, int ncols, u16* __restrict__ dstHi,
    u16* __restrict__ dstLo, int lo_n) {
  __shared__ float tl[64][65];
  const int t = threadIdx.x;
  const int n0 = blockIdx.x * 64, k0 = blockIdx.y * 64;
#pragma unroll
  for (int i = 0; i < 16; i++) {
    const int idx = i * 256 + t, r = idx >> 6, c = idx & 63;
    tl[r][c] = src[(size_t)(k0 + r) * ncols + n0 + c];
  }
  __syncthreads();
#pragma unroll
  for (int i = 0; i < 16; i++) {
    const int idx = i * 256 + t, nl = idx >> 6, kk = idx & 63;
    const float v = tl[kk][nl];
    const u16 hi = f2bf(v);
    dstHi[(size_t)(n0 + nl) * 1024 + k0 + kk] = hi;
    if (n0 + nl < lo_n)
      dstLo[(size_t)(n0 + nl) * 1024 + k0 + kk] = f2bf(v - bf2f(hi));
  }
}

// ============ GEMM variants ============
// qk: 3-term split GEMM over n in [0,2048). Epilogue: head-major hi/lo split
// (k pre-scaled by scale_q*scale_k) + fused global sum-of-squares (raw values).
__global__ __launch_bounds__(256) void gemm_qk_kernel(
    const u16* __restrict__ Ah, const u16* __restrict__ Al,
    const u16* __restrict__ Bht, const u16* __restrict__ Blt,
    u16* __restrict__ qh, u16* __restrict__ ql, u16* __restrict__ kh,
    u16* __restrict__ kl, const float* __restrict__ scale_q,
    const float* __restrict__ scale_k, float* __restrict__ sums) {
  __shared__ u16 As[128 * 32], Bs[128 * 32];
  const int tid = threadIdx.x;
  const int bn = blockIdx.x * 128, bm = blockIdx.y * 128;
  const f32x4 z4 = {0.f, 0.f, 0.f, 0.f};
  f32x4 acc[4][4];
#pragma unroll
  for (int i = 0; i < 4; i++)
#pragma unroll
    for (int j = 0; j < 4; j++) acc[i][j] = z4;
  gemm_core_seg(Ah, Bht, bm, bn, As, Bs, acc, tid);  // xh * Wh
  gemm_core_seg(Al, Bht, bm, bn, As, Bs, acc, tid);  // xl * Wh
  gemm_core_seg(Ah, Blt, bm, bn, As, Bs, acc, tid);  // xh * Wl

  const int wv = tid >> 6, lane = tid & 63, lm = lane & 15, quad = lane >> 4;
  const int wr = (wv >> 1) * 64, wc = (wv & 1) * 64;
  const bool is_k = (bn >= 1024);  // block-uniform (128 | 1024)
  u16* dh = is_k ? kh : qh;
  u16* dl = is_k ? kl : ql;
  float ss = 0.f;
#pragma unroll
  for (int ni = 0; ni < 4; ni++) {
    const int col = bn + wc + ni * 16 + lm;
    const int d = col & 63, hh = (col >> 6) & 15;
    const float sc = is_k ? scale_q[d] * scale_k[d] : 1.f;
#pragma unroll
    for (int mi = 0; mi < 4; mi++) {
#pragma unroll
      for (int i = 0; i < 4; i++) {
        const int row = bm + wr + mi * 16 + quad * 4 + i;
        const float a = acc[mi][ni][i];
        ss += a * a;  // raw (pre-scale) for global RMS
        const float v = a * sc;
        const u16 hi = f2bf(v);
        const size_t o =
            (((size_t)((row >> 10) * 16 + hh)) * 1024 + (row & 1023)) * 64 + d;
        dh[o] = hi;
        dl[o] = f2bf(v - bf2f(hi));
      }
    }
  }
#pragma unroll
  for (int m = 32; m >= 1; m >>= 1) ss += __shfl_xor(ss, m, 64);
  if (lane == 0) atomicAdd(&sums[is_k ? 1 : 0], ss);
}

// v: plain bf16 GEMM; epilogue writes v TRANSPOSED head-major: vT[b][h][d][s]
__global__ __launch_bounds__(256) void gemm_v_kernel(
    const u16* __restrict__ Ah, const u16* __restrict__ Bv,
    u16* __restrict__ vT) {
  __shared__ u16 As[128 * 32], Bs[128 * 32];
  const int tid = threadIdx.x;
  const int bn = blockIdx.x * 128, bm = blockIdx.y * 128;
  const f32x4 z4 = {0.f, 0.f, 0.f, 0.f};
  f32x4 acc[4][4];
#pragma unroll
  for (int i = 0; i < 4; i++)
#pragma unroll
    for (int j = 0; j < 4; j++) acc[i][j] = z4;
  gemm_core_seg(Ah, Bv, bm, bn, As, Bs, acc, tid);
  const int wv = tid >> 6, lane = tid & 63, lm = lane & 15, quad = lane >> 4;
  const int wr = (wv >> 1) * 64, wc = (wv & 1) * 64;
#pragma unroll
  for (int ni = 0; ni < 4; ni++) {
    const int col = bn + wc + ni * 16 + lm;
    const int d = col & 63, hh = col >> 6;
#pragma unroll
    for (int mi = 0; mi < 4; mi++) {
#pragma unroll
      for (int i = 0; i < 4; i++) {
        const int row = bm + wr + mi * 16 + quad * 4 + i;
        const size_t o =
            (((size_t)((row >> 10) * 16 + hh)) * 64 + d) * 1024 + (row & 1023);
        vT[o] = f2bf(acc[mi][ni][i]);
      }
    }
  }
}

// output projection: z(bf16) @ Wo^T(bf16) -> fp32 out
__global__ __launch_bounds__(256) void gemm_o_kernel(
    const u16* __restrict__ Az, const u16* __restrict__ Bw,
    float* __restrict__ out) {
  __shared__ u16 As[128 * 32], Bs[128 * 32];
  const int tid = threadIdx.x;
  const int bn = blockIdx.x * 128, bm = blockIdx.y * 128;
  const f32x4 z4 = {0.f, 0.f, 0.f, 0.f};
  f32x4 acc[4][4];
#pragma unroll
  for (int i = 0; i < 4; i++)
#pragma unroll
    for (int j = 0; j < 4; j++) acc[i][j] = z4;
  gemm_core_seg(Az, Bw, bm, bn, As, Bs, acc, tid);
  const int wv = tid >> 6, lane = tid & 63, lm = lane & 15, quad = lane >> 4;
  const int wr = (wv >> 1) * 64, wc = (wv & 1) * 64;
#pragma unroll
  for (int ni = 0; ni < 4; ni++) {
    const int col = bn + wc + ni * 16 + lm;
#pragma unroll
    for (int mi = 0; mi < 4; mi++) {
#pragma unroll
      for (int i = 0; i < 4; i++) {
        const int row = bm + wr + mi * 16 + quad * 4 + i;
        out[(size_t)row * 1024 + col] = acc[mi][ni][i];
      }
    }
  }
}

// ============ fused attention ============
// grid (16 qtiles, 16 heads, 4 batch), 256 thr. Wave w owns q-rows
// qt*64 + w*16. QK: 3-term split bf16 MFMA; fixed-shift softmax exp(l*cs-60);
// PV: bf16 MFMA with vT staged. XOR-swizzled LDS (128B rows wrap 32 banks).
__global__ __launch_bounds__(256) void attn_kernel(
    const u16* __restrict__ qh, const u16* __restrict__ ql,
    const u16* __restrict__ kh, const u16* __restrict__ kl,
    const u16* __restrict__ vT, const float* __restrict__ sums,
    u16* __restrict__ z) {
  __shared__ u16 khs[4096], kls[4096], vts[4096];
  __shared__ u16 pb[4][1024];
  const int tid = threadIdx.x, wv = tid >> 6, lane = tid & 63;
  const int lm = lane & 15, quad = lane >> 4;
  const int qt = blockIdx.x, hh = blockIdx.y, b = blockIdx.z;
  const float inv_rq = 1.f / (sqrtf(sums[0] * (1.f / 4194304.f)) + 1e-6f);
  const float inv_rk = 1.f / (sqrtf(sums[1] * (1.f / 4194304.f)) + 1e-6f);
  const float cs = inv_rq * inv_rk;
  const size_t ho = ((size_t)(b * 16 + hh)) << 16;  // head offset (1024*64)
  const int qrow = qt * 64 + wv * 16 + lm;
  bf16x8 aH[2], aL[2];
  aH[0] = *(const bf16x8*)&qh[ho + (size_t)qrow * 64 + quad * 8];
  aH[1] = *(const bf16x8*)&qh[ho + (size_t)qrow * 64 + 32 + quad * 8];
  aL[0] = *(const bf16x8*)&ql[ho + (size_t)qrow * 64 + quad * 8];
  aL[1] = *(const bf16x8*)&ql[ho + (size_t)qrow * 64 + 32 + quad * 8];
  const f32x4 zz = {0.f, 0.f, 0.f, 0.f};
  f32x4 zac[4] = {zz, zz, zz, zz};
  float rs[4] = {0.f, 0.f, 0.f, 0.f};

  for (int it = 0; it < 16; it++) {
    __syncthreads();
    const u16* ksrc = kh + ho + it * 4096;
    const u16* lsrc = kl + ho + it * 4096;
    const u16* vsrc = vT + ho + it * 64;
#pragma unroll
    for (int j = 0; j < 2; j++) {
      const int inst = wv * 2 + j;
      const int r = inst * 8 + (lane >> 3);      // tile row this lane feeds
      const int lc = (lane & 7) ^ (r & 7);       // logical 16B chunk (swizzle)
      gl_lds16(ksrc + r * 64 + lc * 8, khs + inst * 512);
      gl_lds16(lsrc + r * 64 + lc * 8, kls + inst * 512);
      gl_lds16(vsrc + (size_t)r * 1024 + lc * 8, vts + inst * 512);
    }
    __syncthreads();
    // ---- QK^T: c[nt] covers keys nt*16+lm, q-rows quad*4+i ----
    f32x4 c[4] = {zz, zz, zz, zz};
#pragma unroll
    for (int nt = 0; nt < 4; nt++) {
      const int row = nt * 16 + lm, sw = row & 7;
      const bf16x8 bH0 = *(const bf16x8*)&khs[row * 64 + ((quad ^ sw) * 8)];
      const bf16x8 bH1 = *(const bf16x8*)&khs[row * 64 + (((4 + quad) ^ sw) * 8)];
      const bf16x8 bL0 = *(const bf16x8*)&kls[row * 64 + ((quad ^ sw) * 8)];
      const bf16x8 bL1 = *(const bf16x8*)&kls[row * 64 + (((4 + quad) ^ sw) * 8)];
      c[nt] = __builtin_amdgcn_mfma_f32_16x16x32_bf16(aH[0], bH0, c[nt], 0, 0, 0);
      c[nt] = __builtin_amdgcn_mfma_f32_16x16x32_bf16(aH[1], bH1, c[nt], 0, 0, 0);
      c[nt] = __builtin_amdgcn_mfma_f32_16x16x32_bf16(aL[0], bH0, c[nt], 0, 0, 0);
      c[nt] = __builtin_amdgcn_mfma_f32_16x16x32_bf16(aL[1], bH1, c[nt], 0, 0, 0);
      c[nt] = __builtin_amdgcn_mfma_f32_16x16x32_bf16(aH[0], bL0, c[nt], 0, 0, 0);
      c[nt] = __builtin_amdgcn_mfma_f32_16x16x32_bf16(aH[1], bL1, c[nt], 0, 0, 0);
    }
    // ---- softmax numerator (fixed shift, no max pass) + P to LDS ----
    u16* pbw = pb[wv];
#pragma unroll
    for (int nt = 0; nt < 4; nt++) {
      const int lchunk = nt * 2 + (lm >> 3);
#pragma unroll
      for (int i = 0; i < 4; i++) {
        const int row = quad * 4 + i;
        const float p = __expf(c[nt][i] * cs - 60.f);
        rs[i] += p;
        pbw[row * 64 + ((lchunk ^ (row & 7)) * 8) + (lm & 7)] = f2bf(p);
      }
    }
    // ---- PV: zac[dt] covers d-cols dt*16+lm ----
#pragma unroll
    for (int ch = 0; ch < 2; ch++) {
      const bf16x8 ap =
          *(const bf16x8*)&pbw[lm * 64 + (((ch * 4 + quad) ^ (lm & 7)) * 8)];
#pragma unroll
      for (int dt = 0; dt < 4; dt++) {
        const int row = dt * 16 + lm;
        const bf16x8 bv =
            *(const bf16x8*)&vts[row * 64 + (((ch * 4 + quad) ^ (row & 7)) * 8)];
        zac[dt] = __builtin_amdgcn_mfma_f32_16x16x32_bf16(ap, bv, zac[dt], 0, 0, 0);
      }
    }
  }
  // row sums across the 16 lm lanes (stays within quad group)
#pragma unroll
  for (int m = 1; m < 16; m <<= 1) {
#pragma unroll
    for (int i = 0; i < 4; i++) rs[i] += __shfl_xor(rs[i], m, 64);
  }
  const int trow = b * 1024 + qt * 64 + wv * 16;
#pragma unroll
  for (int dt = 0; dt < 4; dt++)
#pragma unroll
    for (int i = 0; i < 4; i++)
      z[(size_t)(trow + quad * 4 + i) * 1024 + hh * 64 + dt * 16 + lm] =
          f2bf(zac[dt][i] / rs[i]);
}

extern "C" void kernel_launch(void* const* d_in, const int* in_sizes, int n_in,
                              void* d_out, int out_size, void* d_ws,
                              size_t ws_size, hipStream_t stream) {
  (void)in_sizes; (void)n_in; (void)out_size; (void)ws_size;
  const float* x = (const float*)d_in[0];
  const float* Wqkv = (const float*)d_in[1];
  const float* Wo = (const float*)d_in[2];
  const float* scale_q = (const float*)d_in[3];
  const float* scale_k = (const float*)d_in[4];
  float* out = (float*)d_out;

  // workspace layout (total ~61 MB, aliases on dead regions):
  char* ws = (char*)d_ws;
  u16* qh = (u16*)(ws + 0);          // [b][h][s][d] bf16 hi, 8.39MB
  u16* ql = (u16*)(ws + 8388608);    // lo
  u16* kh = (u16*)(ws + 16777216);   // (scaled by sq*sk) hi
  u16* kl = (u16*)(ws + 25165824);   // lo
  u16* Ah = (u16*)(ws + 33554432);   // x hi [4096][1024]
  u16* Al = (u16*)(ws + 41943040);   // x lo
  u16* Bht = (u16*)(ws + 50331648);  // Wqkv^T hi [3072][1024]
  u16* Blt = (u16*)(ws + 56623104);  // Wqkv^T lo [2048][1024] (q,k cols only)
  u16* vT = Al;                      // alias: written after Al is dead
  u16* z = Bht;                      // alias: written after Bht/Blt are dead
  u16* Wot = Ah;                     // alias: converted after Ah is dead
  float* sums = (float*)(ws + 60817408);

  conv_x_kernel<<<4096, 256, 0, stream>>>(x, Ah, Al);
  conv_wT_kernel<<<dim3(48, 16), 256, 0, stream>>>(Wqkv, 3072, Bht, Blt, 2048);
  hipMemsetAsync(sums, 0, 2 * sizeof(float), stream);
  gemm_qk_kernel<<<dim3(16, 32), 256, 0, stream>>>(Ah, Al, Bht, Blt, qh, ql, kh,
                                                   kl, scale_q, scale_k, sums);
  gemm_v_kernel<<<dim3(8, 32), 256, 0, stream>>>(
      Ah, Bht + (size_t)2048 * 1024, vT);
  conv_wT_kernel<<<dim3(16, 16), 256, 0, stream>>>(Wo, 1024, Wot, nullptr, 0);
  attn_kernel<<<dim3(16, 16, 4), 256, 0, stream>>>(qh, ql, kh, kl, vT, sums, z);
  gemm_o_kernel<<<dim3(8, 32), 256, 0, stream>>>(z, Wot, out);
}

// Round 3
// 263.180 us; speedup vs baseline: 3.0584x; 1.1052x over previous
//
#include <hip/hip_runtime.h>

typedef float f32x4 __attribute__((ext_vector_type(4)));
typedef short bf16x8 __attribute__((ext_vector_type(8)));
typedef unsigned short u16;

__device__ __forceinline__ u16 f2bf(float f) {
  unsigned int u = __float_as_uint(f);
  u = u + 0x7fffu + ((u >> 16) & 1u);  // round-to-nearest-even
  return (u16)(u >> 16);
}
__device__ __forceinline__ float bf2f(u16 h) {
  return __uint_as_float(((unsigned int)h) << 16);
}

typedef unsigned int as1_uint __attribute__((address_space(1)));
typedef unsigned int as3_uint __attribute__((address_space(3)));
// async global->LDS, 16B per lane; LDS dest = wave-uniform base + lane*16
__device__ __forceinline__ void gl_lds16(const void* g, void* l) {
  __builtin_amdgcn_global_load_lds((as1_uint*)g, (as3_uint*)l, 16, 0, 0);
}

// ============ converts ============
__global__ __launch_bounds__(256) void conv_x_kernel(const float* __restrict__ x,
                                                     u16* __restrict__ Ah) {
  const int idx = blockIdx.x * 256 + threadIdx.x;  // 4 elems per thread
  const float4 v = ((const float4*)x)[idx];
  ushort4 h;
  h.x = f2bf(v.x); h.y = f2bf(v.y); h.z = f2bf(v.z); h.w = f2bf(v.w);
  ((ushort4*)Ah)[idx] = h;
}

// transpose-convert: dstHi[n][k] = hi(src[k][n]); lo written for n < lo_n.
__global__ __launch_bounds__(256) void conv_wT_kernel(
    const float* __restrict__ src, int ncols, u16* __restrict__ dstHi,
    u16* __restrict__ dstLo, int lo_n) {
  __shared__ float tl[64][65];
  const int t = threadIdx.x;
  const int n0 = blockIdx.x * 64, k0 = blockIdx.y * 64;
#pragma unroll
  for (int i = 0; i < 16; i++) {
    const int idx = i * 256 + t, r = idx >> 6, c = idx & 63;
    tl[r][c] = src[(size_t)(k0 + r) * ncols + n0 + c];
  }
  __syncthreads();
#pragma unroll
  for (int i = 0; i < 16; i++) {
    const int idx = i * 256 + t, nl = idx >> 6, kk = idx & 63;
    const float v = tl[kk][nl];
    const u16 hi = f2bf(v);
    dstHi[(size_t)(n0 + nl) * 1024 + k0 + kk] = hi;
    if (n0 + nl < lo_n)
      dstLo[(size_t)(n0 + nl) * 1024 + k0 + kk] = f2bf(v - bf2f(hi));
  }
}

// ============ fused qkv GEMM ============
// Grid (24,32): bn = 128-col slab of the 3072 outputs, bm = 128-row s slab.
// qk blocks (bn<2048): 2-term split  xh*Wh + xh*Wl  in SWAPPED orientation
//   (D rows = output dims -> lane holds 4 consecutive d -> dwordx2 stores).
// v blocks: plain bf16, normal orientation (lane holds 4 consecutive s ->
//   contiguous in vT[d][s]).
// LDS chunk swizzle P(row,q)=row*4+(q^((row>>1)&3)) -> 2-way banks (free).
__global__ __launch_bounds__(256) void gemm_qkv_kernel(
    const u16* __restrict__ Ah, const u16* __restrict__ Bht,
    const u16* __restrict__ Blt, u16* __restrict__ qh, u16* __restrict__ ql,
    u16* __restrict__ kh, u16* __restrict__ kl, u16* __restrict__ vT,
    const float* __restrict__ scale_q, const float* __restrict__ scale_k,
    float* __restrict__ sums) {
  __shared__ u16 XhS[128 * 32], WhS[128 * 32], WlS[128 * 32];
  const int tid = threadIdx.x, wv = tid >> 6, lane = tid & 63;
  const int lm = lane & 15, quad = lane >> 4;
  const int bn = blockIdx.x * 128, bm = blockIdx.y * 128;
  const bool is_v = (bn >= 2048);
  const int wr = (wv >> 1) * 64, wc = (wv & 1) * 64;
  const int arow = lane >> 2;                             // 4 lanes per row
  const int acol = (((lane & 3) ^ ((lane >> 3) & 3)) * 8);  // swizzled chunk
  const int fq = (quad ^ ((lm >> 1) & 3)) * 8;              // frag-read chunk

  const f32x4 z4 = {0.f, 0.f, 0.f, 0.f};
  f32x4 acc[4][4];
#pragma unroll
  for (int i = 0; i < 4; i++)
#pragma unroll
    for (int j = 0; j < 4; j++) acc[i][j] = z4;

  const u16* Xg = Ah + (size_t)bm * 1024;
  const u16* Whg = Bht + (size_t)bn * 1024;
  const u16* Wlg = Blt + (size_t)bn * 1024;  // only dereferenced if !is_v

  for (int k0 = 0; k0 < 1024; k0 += 32) {
    __syncthreads();
#pragma unroll
    for (int j = 0; j < 2; j++) {
      const int r = wv * 32 + j * 16;
      gl_lds16(Xg + (size_t)(r + arow) * 1024 + k0 + acol, XhS + r * 32);
      gl_lds16(Whg + (size_t)(r + arow) * 1024 + k0 + acol, WhS + r * 32);
      if (!is_v)
        gl_lds16(Wlg + (size_t)(r + arow) * 1024 + k0 + acol, WlS + r * 32);
    }
    __syncthreads();
    if (!is_v) {
      bf16x8 wh[4], wl[4];
#pragma unroll
      for (int mi = 0; mi < 4; mi++) {
        wh[mi] = *(const bf16x8*)&WhS[(wr + mi * 16 + lm) * 32 + fq];
        wl[mi] = *(const bf16x8*)&WlS[(wr + mi * 16 + lm) * 32 + fq];
      }
#pragma unroll
      for (int ni = 0; ni < 4; ni++) {
        const bf16x8 xh = *(const bf16x8*)&XhS[(wc + ni * 16 + lm) * 32 + fq];
#pragma unroll
        for (int mi = 0; mi < 4; mi++) {
          acc[mi][ni] = __builtin_amdgcn_mfma_f32_16x16x32_bf16(
              wh[mi], xh, acc[mi][ni], 0, 0, 0);
          acc[mi][ni] = __builtin_amdgcn_mfma_f32_16x16x32_bf16(
              wl[mi], xh, acc[mi][ni], 0, 0, 0);
        }
      }
    } else {
      bf16x8 xf[4];
#pragma unroll
      for (int mi = 0; mi < 4; mi++)
        xf[mi] = *(const bf16x8*)&XhS[(wr + mi * 16 + lm) * 32 + fq];
#pragma unroll
      for (int ni = 0; ni < 4; ni++) {
        const bf16x8 wf = *(const bf16x8*)&WhS[(wc + ni * 16 + lm) * 32 + fq];
#pragma unroll
        for (int mi = 0; mi < 4; mi++)
          acc[mi][ni] = __builtin_amdgcn_mfma_f32_16x16x32_bf16(
              xf[mi], wf, acc[mi][ni], 0, 0, 0);
      }
    }
  }

  if (!is_v) {
    // swapped orientation: acc[mi][ni][i] = C[col = bn+wr+mi*16+quad*4+i]
    //                                        [s  = bm+wc+ni*16+lm]
    const bool is_k = (bn >= 1024);
    u16* dh = is_k ? kh : qh;
    u16* dl = is_k ? kl : ql;
    float ss = 0.f;
#pragma unroll
    for (int mi = 0; mi < 4; mi++) {
      const int col0 = bn + wr + mi * 16 + quad * 4;
      const int d0 = col0 & 63, hh = (col0 >> 6) & 15;
      float sc[4] = {1.f, 1.f, 1.f, 1.f};
      if (is_k) {
        const float4 sq = *(const float4*)&scale_q[d0];
        const float4 sk = *(const float4*)&scale_k[d0];
        sc[0] = sq.x * sk.x; sc[1] = sq.y * sk.y;
        sc[2] = sq.z * sk.z; sc[3] = sq.w * sk.w;
      }
#pragma unroll
      for (int ni = 0; ni < 4; ni++) {
        const int s = bm + wc + ni * 16 + lm;
        const int b = s >> 10, sl = s & 1023;
        const size_t o = (((size_t)(b * 16 + hh)) * 1024 + sl) * 64 + d0;
        ushort4 h4, l4;
#pragma unroll
        for (int i = 0; i < 4; i++) {
          const float a = acc[mi][ni][i];
          ss += a * a;  // raw (pre-scale) for global RMS
          const float v = a * sc[i];
          const u16 hi = f2bf(v);
          const u16 lo = f2bf(v - bf2f(hi));
          if (i == 0) { h4.x = hi; l4.x = lo; }
          else if (i == 1) { h4.y = hi; l4.y = lo; }
          else if (i == 2) { h4.z = hi; l4.z = lo; }
          else { h4.w = hi; l4.w = lo; }
        }
        *(ushort4*)&dh[o] = h4;
        *(ushort4*)&dl[o] = l4;
      }
    }
#pragma unroll
    for (int m = 32; m >= 1; m >>= 1) ss += __shfl_xor(ss, m, 64);
    if (lane == 0) atomicAdd(&sums[is_k ? 1 : 0], ss);
  } else {
    // normal orientation: acc[mi][ni][i] = C[s = bm+wr+mi*16+quad*4+i]
    //                                       [col = (bn)+wc+ni*16+lm]
#pragma unroll
    for (int ni = 0; ni < 4; ni++) {
      const int colv = (bn - 2048) + wc + ni * 16 + lm;
      const int d = colv & 63, hh = colv >> 6;
#pragma unroll
      for (int mi = 0; mi < 4; mi++) {
        const int s0 = bm + wr + mi * 16 + quad * 4;
        const int b = s0 >> 10, sl = s0 & 1023;
        ushort4 v4;
        v4.x = f2bf(acc[mi][ni][0]);
        v4.y = f2bf(acc[mi][ni][1]);
        v4.z = f2bf(acc[mi][ni][2]);
        v4.w = f2bf(acc[mi][ni][3]);
        *(ushort4*)&vT[(((size_t)(b * 16 + hh)) * 64 + d) * 1024 + sl] = v4;
      }
    }
  }
}

// ============ output projection (swapped orientation) ============
__global__ __launch_bounds__(256) void gemm_o_kernel(const u16* __restrict__ Az,
                                                     const u16* __restrict__ Bw,
                                                     float* __restrict__ out) {
  __shared__ u16 Ws[128 * 32], Zs[128 * 32];
  const int tid = threadIdx.x, wv = tid >> 6, lane = tid & 63;
  const int lm = lane & 15, quad = lane >> 4;
  const int bn = blockIdx.x * 128, bm = blockIdx.y * 128;
  const int wr = (wv >> 1) * 64, wc = (wv & 1) * 64;
  const int arow = lane >> 2;
  const int acol = (((lane & 3) ^ ((lane >> 3) & 3)) * 8);
  const int fq = (quad ^ ((lm >> 1) & 3)) * 8;
  const f32x4 z4 = {0.f, 0.f, 0.f, 0.f};
  f32x4 acc[4][4];
#pragma unroll
  for (int i = 0; i < 4; i++)
#pragma unroll
    for (int j = 0; j < 4; j++) acc[i][j] = z4;
  const u16* Zg = Az + (size_t)bm * 1024;
  const u16* Wg = Bw + (size_t)bn * 1024;
  for (int k0 = 0; k0 < 1024; k0 += 32) {
    __syncthreads();
#pragma unroll
    for (int j = 0; j < 2; j++) {
      const int r = wv * 32 + j * 16;
      gl_lds16(Wg + (size_t)(r + arow) * 1024 + k0 + acol, Ws + r * 32);
      gl_lds16(Zg + (size_t)(r + arow) * 1024 + k0 + acol, Zs + r * 32);
    }
    __syncthreads();
    bf16x8 wf[4];
#pragma unroll
    for (int mi = 0; mi < 4; mi++)
      wf[mi] = *(const bf16x8*)&Ws[(wr + mi * 16 + lm) * 32 + fq];
#pragma unroll
    for (int ni = 0; ni < 4; ni++) {
      const bf16x8 zf = *(const bf16x8*)&Zs[(wc + ni * 16 + lm) * 32 + fq];
#pragma unroll
      for (int mi = 0; mi < 4; mi++)
        acc[mi][ni] = __builtin_amdgcn_mfma_f32_16x16x32_bf16(
            wf[mi], zf, acc[mi][ni], 0, 0, 0);
    }
  }
#pragma unroll
  for (int mi = 0; mi < 4; mi++) {
    const int col0 = bn + wr + mi * 16 + quad * 4;
#pragma unroll
    for (int ni = 0; ni < 4; ni++) {
      const int s = bm + wc + ni * 16 + lm;
      const float4 o = {acc[mi][ni][0], acc[mi][ni][1], acc[mi][ni][2],
                        acc[mi][ni][3]};
      *(float4*)&out[(size_t)s * 1024 + col0] = o;
    }
  }
}

// ============ fused attention ============
__global__ __launch_bounds__(256) void attn_kernel(
    const u16* __restrict__ qh, const u16* __restrict__ ql,
    const u16* __restrict__ kh, const u16* __restrict__ kl,
    const u16* __restrict__ vT, const float* __restrict__ sums,
    u16* __restrict__ z) {
  __shared__ u16 khs[4096], kls[4096], vts[4096];
  __shared__ u16 pb[4][1024];
  __shared__ float rsw[4][16];
  const int tid = threadIdx.x, wv = tid >> 6, lane = tid & 63;
  const int lm = lane & 15, quad = lane >> 4;
  const int qt = blockIdx.x, hh = blockIdx.y, b = blockIdx.z;
  const float inv_rq = 1.f / (sqrtf(sums[0] * (1.f / 4194304.f)) + 1e-6f);
  const float inv_rk = 1.f / (sqrtf(sums[1] * (1.f / 4194304.f)) + 1e-6f);
  const float cs = inv_rq * inv_rk;
  const size_t ho = ((size_t)(b * 16 + hh)) << 16;  // head offset (1024*64)
  const int qrow = qt * 64 + wv * 16 + lm;
  bf16x8 aH[2], aL[2];
  aH[0] = *(const bf16x8*)&qh[ho + (size_t)qrow * 64 + quad * 8];
  aH[1] = *(const bf16x8*)&qh[ho + (size_t)qrow * 64 + 32 + quad * 8];
  aL[0] = *(const bf16x8*)&ql[ho + (size_t)qrow * 64 + quad * 8];
  aL[1] = *(const bf16x8*)&ql[ho + (size_t)qrow * 64 + 32 + quad * 8];
  const f32x4 zz = {0.f, 0.f, 0.f, 0.f};
  f32x4 zac[4] = {zz, zz, zz, zz};
  float rs[4] = {0.f, 0.f, 0.f, 0.f};

  for (int it = 0; it < 16; it++) {
    __syncthreads();
    const u16* ksrc = kh + ho + it * 4096;
    const u16* lsrc = kl + ho + it * 4096;
    const u16* vsrc = vT + ho + it * 64;
#pragma unroll
    for (int j = 0; j < 2; j++) {
      const int inst = wv * 2 + j;
      const int r = inst * 8 + (lane >> 3);
      const int lc = (lane & 7) ^ (r & 7);
      gl_lds16(ksrc + r * 64 + lc * 8, khs + inst * 512);
      gl_lds16(lsrc + r * 64 + lc * 8, kls + inst * 512);
      gl_lds16(vsrc + (size_t)r * 1024 + lc * 8, vts + inst * 512);
    }
    __syncthreads();
    // ---- QK^T (A=q rows, B=k rows): c[nt] keys nt*16+lm, q-rows quad*4+i
    f32x4 c[4] = {zz, zz, zz, zz};
#pragma unroll
    for (int nt = 0; nt < 4; nt++) {
      const int row = nt * 16 + lm, sw = row & 7;
      const bf16x8 bH0 = *(const bf16x8*)&khs[row * 64 + ((quad ^ sw) * 8)];
      const bf16x8 bH1 = *(const bf16x8*)&khs[row * 64 + (((4 + quad) ^ sw) * 8)];
      const bf16x8 bL0 = *(const bf16x8*)&kls[row * 64 + ((quad ^ sw) * 8)];
      const bf16x8 bL1 = *(const bf16x8*)&kls[row * 64 + (((4 + quad) ^ sw) * 8)];
      c[nt] = __builtin_amdgcn_mfma_f32_16x16x32_bf16(aH[0], bH0, c[nt], 0, 0, 0);
      c[nt] = __builtin_amdgcn_mfma_f32_16x16x32_bf16(aH[1], bH1, c[nt], 0, 0, 0);
      c[nt] = __builtin_amdgcn_mfma_f32_16x16x32_bf16(aL[0], bH0, c[nt], 0, 0, 0);
      c[nt] = __builtin_amdgcn_mfma_f32_16x16x32_bf16(aL[1], bH1, c[nt], 0, 0, 0);
      c[nt] = __builtin_amdgcn_mfma_f32_16x16x32_bf16(aH[0], bL0, c[nt], 0, 0, 0);
      c[nt] = __builtin_amdgcn_mfma_f32_16x16x32_bf16(aH[1], bL1, c[nt], 0, 0, 0);
    }
    // ---- softmax numerator (fixed shift) + P to LDS ----
    u16* pbw = pb[wv];
#pragma unroll
    for (int nt = 0; nt < 4; nt++) {
      const int lchunk = nt * 2 + (lm >> 3);
#pragma unroll
      for (int i = 0; i < 4; i++) {
        const int row = quad * 4 + i;
        const float p = __expf(c[nt][i] * cs - 60.f);
        rs[i] += p;
        pbw[row * 64 + ((lchunk ^ (row & 7)) * 8) + (lm & 7)] = f2bf(p);
      }
    }
    // ---- PV swapped (A=v rows=d, B=p rows=q): zac[dt] rows d=dt*16+quad*4+i,
    //      cols q=lm ----
#pragma unroll
    for (int ch = 0; ch < 2; ch++) {
      const bf16x8 ap =
          *(const bf16x8*)&pbw[lm * 64 + (((ch * 4 + quad) ^ (lm & 7)) * 8)];
#pragma unroll
      for (int dt = 0; dt < 4; dt++) {
        const int row = dt * 16 + lm;
        const bf16x8 bv =
            *(const bf16x8*)&vts[row * 64 + (((ch * 4 + quad) ^ (row & 7)) * 8)];
        zac[dt] = __builtin_amdgcn_mfma_f32_16x16x32_bf16(bv, ap, zac[dt], 0, 0, 0);
      }
    }
  }
  // rowsum: reduce across lm lanes, then redistribute so lane lm gets row lm
#pragma unroll
  for (int m = 1; m < 16; m <<= 1) {
#pragma unroll
    for (int i = 0; i < 4; i++) rs[i] += __shfl_xor(rs[i], m, 64);
  }
  if (lm == 0) {
#pragma unroll
    for (int i = 0; i < 4; i++) rsw[wv][quad * 4 + i] = rs[i];
  }
  __syncthreads();
  const float inv_rs = 1.f / rsw[wv][lm];
  const size_t zrow = ((size_t)(b * 1024 + qt * 64 + wv * 16 + lm)) * 1024 +
                      hh * 64 + quad * 4;
#pragma unroll
  for (int dt = 0; dt < 4; dt++) {
    ushort4 o;
    o.x = f2bf(zac[dt][0] * inv_rs);
    o.y = f2bf(zac[dt][1] * inv_rs);
    o.z = f2bf(zac[dt][2] * inv_rs);
    o.w = f2bf(zac[dt][3] * inv_rs);
    *(ushort4*)&z[zrow + dt * 16] = o;
  }
}

extern "C" void kernel_launch(void* const* d_in, const int* in_sizes, int n_in,
                              void* d_out, int out_size, void* d_ws,
                              size_t ws_size, hipStream_t stream) {
  (void)in_sizes; (void)n_in; (void)out_size; (void)ws_size;
  const float* x = (const float*)d_in[0];
  const float* Wqkv = (const float*)d_in[1];
  const float* Wo = (const float*)d_in[2];
  const float* scale_q = (const float*)d_in[3];
  const float* scale_k = (const float*)d_in[4];
  float* out = (float*)d_out;

  // workspace (~61 MB):
  char* ws = (char*)d_ws;
  u16* qh = (u16*)(ws + 0);          // [b][h][s][d] bf16 hi
  u16* ql = (u16*)(ws + 8388608);    // lo
  u16* kh = (u16*)(ws + 16777216);   // (scaled) hi
  u16* kl = (u16*)(ws + 25165824);   // lo
  u16* Ah = (u16*)(ws + 33554432);   // x hi [4096][1024]
  u16* vT = (u16*)(ws + 41943040);   // [b][h][d][s] bf16
  u16* Bht = (u16*)(ws + 50331648);  // Wqkv^T hi [3072][1024]
  u16* Blt = (u16*)(ws + 56623104);  // Wqkv^T lo [2048][1024]
  u16* z = Bht;                      // alias: written after Bht/Blt dead
  u16* Wot = Ah;                     // alias: converted after Ah dead
  float* sums = (float*)(ws + 60817408);

  conv_x_kernel<<<4096, 256, 0, stream>>>(x, Ah);
  conv_wT_kernel<<<dim3(48, 16), 256, 0, stream>>>(Wqkv, 3072, Bht, Blt, 2048);
  hipMemsetAsync(sums, 0, 2 * sizeof(float), stream);
  gemm_qkv_kernel<<<dim3(24, 32), 256, 0, stream>>>(
      Ah, Bht, Blt, qh, ql, kh, kl, vT, scale_q, scale_k, sums);
  conv_wT_kernel<<<dim3(16, 16), 256, 0, stream>>>(Wo, 1024, Wot, nullptr, 0);
  attn_kernel<<<dim3(16, 16, 4), 256, 0, stream>>>(qh, ql, kh, kl, vT, sums, z);
  gemm_o_kernel<<<dim3(8, 32), 256, 0, stream>>>(z, Wot, out);
}

// Round 4
// 254.163 us; speedup vs baseline: 3.1669x; 1.0355x over previous
//
#include <hip/hip_runtime.h>

typedef float f32x4 __attribute__((ext_vector_type(4)));
typedef short bf16x8 __attribute__((ext_vector_type(8)));
typedef unsigned short u16;

__device__ __forceinline__ u16 f2bf(float f) {
  unsigned int u = __float_as_uint(f);
  u = u + 0x7fffu + ((u >> 16) & 1u);  // round-to-nearest-even
  return (u16)(u >> 16);
}
__device__ __forceinline__ float bf2f(u16 h) {
  return __uint_as_float(((unsigned int)h) << 16);
}

typedef unsigned int as1_uint __attribute__((address_space(1)));
typedef unsigned int as3_uint __attribute__((address_space(3)));
// async global->LDS, 16B/lane; LDS dest = wave-uniform base + lane*16
__device__ __forceinline__ void gl_lds16(const void* g, void* l) {
  __builtin_amdgcn_global_load_lds((as1_uint*)g, (as3_uint*)l, 16, 0, 0);
}

// Image unit = 8KB: [128 rows][32 k] bf16, chunk swizzle c' = c ^ ((r>>1)&3).
// GEMM operands: [slab][kstep][4096 elems]. Staging is contiguous; frag read
// offset within image: r*32 + ((quad ^ ((lm>>1)&3))*8)  — measured 0-conflict.

// ============ conv_x: x (4096x1024 f32) -> X' images (32 slabs x 32 ksteps)
__global__ __launch_bounds__(256) void conv_x_kernel(const float* __restrict__ x,
                                                     u16* __restrict__ Xp) {
  const int g = blockIdx.x * 256 + threadIdx.x;  // chunk id (16B), 524288 total
  const int o = g * 8;                           // elem offset in X'
  const int slab = o >> 17;
  const int rem = o & 131071;
  const int kstep = rem >> 12;
  const int rem2 = rem & 4095;
  const int r = rem2 >> 5;
  const int cp = (rem2 & 31) >> 3;
  const int c = cp ^ ((r >> 1) & 3);
  const int s = slab * 128 + r;
  const int k = kstep * 32 + c * 8;
  const float4 v0 = *(const float4*)&x[(size_t)s * 1024 + k];
  const float4 v1 = *(const float4*)&x[(size_t)s * 1024 + k + 4];
  ushort4 a, b;
  a.x = f2bf(v0.x); a.y = f2bf(v0.y); a.z = f2bf(v0.z); a.w = f2bf(v0.w);
  b.x = f2bf(v1.x); b.y = f2bf(v1.y); b.z = f2bf(v1.z); b.w = f2bf(v1.w);
  *(ushort4*)&Xp[o] = a;
  *(ushort4*)&Xp[o + 4] = b;
}

// ============ conv_w: W (1024 x ncols f32, k-major rows) -> W'^T images
// Block = (slab of 128 n-cols, group of 64 k). dstLo written for slab<lo_slabs.
__global__ __launch_bounds__(256) void conv_w_kernel(
    const float* __restrict__ src, int ncols, u16* __restrict__ dstHi,
    u16* __restrict__ dstLo, int lo_slabs) {
  __shared__ float tl[64][132];
  const int t = threadIdx.x;
  const int slab = blockIdx.x, kg = blockIdx.y;
  const int n0 = slab * 128, k0 = kg * 64;
#pragma unroll
  for (int i = 0; i < 8; i++) {
    const int fidx = i * 256 + t;
    const int r = fidx >> 5, c4 = (fidx & 31) * 4;
    *(float4*)&tl[r][c4] = *(const float4*)&src[(size_t)(k0 + r) * ncols + n0 + c4];
  }
  __syncthreads();
  const bool lo = slab < lo_slabs;
  const size_t base = (size_t)slab * 131072 + (size_t)(kg * 2) * 4096;
#pragma unroll
  for (int i = 0; i < 4; i++) {
    const int g = i * 256 + t;          // chunk within the 2 images
    const int img = g >> 9, ci = g & 511;
    const int r = ci >> 2, cp = ci & 3;
    const int c = cp ^ ((r >> 1) & 3);
    const int klc = img * 32 + c * 8;
    ushort4 h0, h1, l0, l1;
    float v[8];
#pragma unroll
    for (int e = 0; e < 8; e++) v[e] = tl[klc + e][r];
    h0.x = f2bf(v[0]); h0.y = f2bf(v[1]); h0.z = f2bf(v[2]); h0.w = f2bf(v[3]);
    h1.x = f2bf(v[4]); h1.y = f2bf(v[5]); h1.z = f2bf(v[6]); h1.w = f2bf(v[7]);
    *(ushort4*)&dstHi[base + g * 8] = h0;
    *(ushort4*)&dstHi[base + g * 8 + 4] = h1;
    if (lo) {
      l0.x = f2bf(v[0] - bf2f(h0.x)); l0.y = f2bf(v[1] - bf2f(h0.y));
      l0.z = f2bf(v[2] - bf2f(h0.z)); l0.w = f2bf(v[3] - bf2f(h0.w));
      l1.x = f2bf(v[4] - bf2f(h1.x)); l1.y = f2bf(v[5] - bf2f(h1.y));
      l1.z = f2bf(v[6] - bf2f(h1.z)); l1.w = f2bf(v[7] - bf2f(h1.w));
      *(ushort4*)&dstLo[base + g * 8] = l0;
      *(ushort4*)&dstLo[base + g * 8 + 4] = l1;
    }
  }
}

// ============ fused qkv GEMM (BK=64, image operands) ============
// qk slabs (bn<16): 2-term split (xh*Wh + xh*Wl), swapped orientation.
// v slabs: plain bf16, normal orientation. Epilogues write attn image layouts.
__global__ __launch_bounds__(256) void gemm_qkv_kernel(
    const u16* __restrict__ Xp, const u16* __restrict__ Whp,
    const u16* __restrict__ Wlp, u16* __restrict__ qh, u16* __restrict__ ql,
    u16* __restrict__ kh, u16* __restrict__ kl, u16* __restrict__ vT,
    const float* __restrict__ scale_q, const float* __restrict__ scale_k,
    float* __restrict__ sums) {
  __shared__ u16 XhS[8192], WhS[8192], WlS[8192];
  const int tid = threadIdx.x, wv = tid >> 6, lane = tid & 63;
  const int lm = lane & 15, quad = lane >> 4;
  const int bnS = blockIdx.x, bmS = blockIdx.y;
  const bool is_v = (bnS >= 16);
  const int wr = (wv >> 1) * 64, wc = (wv & 1) * 64;
  const int fq = (quad ^ ((lm >> 1) & 3)) * 8;
  const u16* Xg = Xp + (size_t)bmS * 131072;
  const u16* Wg = Whp + (size_t)bnS * 131072;
  const u16* Lg = Wlp + (size_t)bnS * 131072;
  const f32x4 z4 = {0.f, 0.f, 0.f, 0.f};
  f32x4 acc[4][4];
#pragma unroll
  for (int i = 0; i < 4; i++)
#pragma unroll
    for (int j = 0; j < 4; j++) acc[i][j] = z4;

  for (int t = 0; t < 16; t++) {
    __syncthreads();
    const size_t tb = (size_t)t * 8192;
#pragma unroll
    for (int j = 0; j < 4; j++) {
      const int dof = (wv * 4 + j) * 512;  // elems
      gl_lds16(Xg + tb + dof + lane * 8, (char*)XhS + dof * 2);
      gl_lds16(Wg + tb + dof + lane * 8, (char*)WhS + dof * 2);
      if (!is_v) gl_lds16(Lg + tb + dof + lane * 8, (char*)WlS + dof * 2);
    }
    __syncthreads();
#pragma unroll
    for (int j = 0; j < 2; j++) {
      const int hb = j * 4096;
      if (!is_v) {
        bf16x8 wh[4], wl[4];
#pragma unroll
        for (int mi = 0; mi < 4; mi++) {
          wh[mi] = *(const bf16x8*)&WhS[hb + (wr + mi * 16 + lm) * 32 + fq];
          wl[mi] = *(const bf16x8*)&WlS[hb + (wr + mi * 16 + lm) * 32 + fq];
        }
#pragma unroll
        for (int ni = 0; ni < 4; ni++) {
          const bf16x8 xh = *(const bf16x8*)&XhS[hb + (wc + ni * 16 + lm) * 32 + fq];
#pragma unroll
          for (int mi = 0; mi < 4; mi++) {
            acc[mi][ni] = __builtin_amdgcn_mfma_f32_16x16x32_bf16(
                wh[mi], xh, acc[mi][ni], 0, 0, 0);
            acc[mi][ni] = __builtin_amdgcn_mfma_f32_16x16x32_bf16(
                wl[mi], xh, acc[mi][ni], 0, 0, 0);
          }
        }
      } else {
        bf16x8 xf[4];
#pragma unroll
        for (int mi = 0; mi < 4; mi++)
          xf[mi] = *(const bf16x8*)&XhS[hb + (wr + mi * 16 + lm) * 32 + fq];
#pragma unroll
        for (int ni = 0; ni < 4; ni++) {
          const bf16x8 wf = *(const bf16x8*)&WhS[hb + (wc + ni * 16 + lm) * 32 + fq];
#pragma unroll
          for (int mi = 0; mi < 4; mi++)
            acc[mi][ni] = __builtin_amdgcn_mfma_f32_16x16x32_bf16(
                xf[mi], wf, acc[mi][ni], 0, 0, 0);
        }
      }
    }
  }

  const int bn = bnS * 128, bm = bmS * 128;
  if (!is_v) {
    // swapped: acc[mi][ni][i] = C[col=bn+wr+mi*16+quad*4+i][s=bm+wc+ni*16+lm]
    const bool is_k = (bnS >= 8);
    u16* dh = is_k ? kh : qh;
    u16* dl = is_k ? kl : ql;
    float ss = 0.f;
#pragma unroll
    for (int mi = 0; mi < 4; mi++) {
      const int col0 = bn + wr + mi * 16 + quad * 4;
      const int hh = (col0 >> 6) & 15, d0 = col0 & 63;
      const int dhi = d0 >> 5, cc = (d0 & 31) >> 3, eo = d0 & 7;
      float sc[4] = {1.f, 1.f, 1.f, 1.f};
      if (is_k) {
        const float4 sq = *(const float4*)&scale_q[d0];
        const float4 sk = *(const float4*)&scale_k[d0];
        sc[0] = sq.x * sk.x; sc[1] = sq.y * sk.y;
        sc[2] = sq.z * sk.z; sc[3] = sq.w * sk.w;
      }
#pragma unroll
      for (int ni = 0; ni < 4; ni++) {
        const int s = bm + wc + ni * 16 + lm;
        const int b = s >> 10, sl = s & 1023, st = sl >> 6, r = sl & 63;
        const size_t off = ((size_t)((b * 16 + hh) * 16 + st)) * 4096 +
                           dhi * 2048 + r * 32 + ((cc ^ ((r >> 1) & 3)) * 8) + eo;
        ushort4 h4, l4;
#pragma unroll
        for (int i = 0; i < 4; i++) {
          const float a = acc[mi][ni][i];
          ss += a * a;  // raw (pre-scale) for global RMS
          const float v = a * sc[i];
          const u16 hi = f2bf(v);
          const u16 lo2 = f2bf(v - bf2f(hi));
          if (i == 0) { h4.x = hi; l4.x = lo2; }
          else if (i == 1) { h4.y = hi; l4.y = lo2; }
          else if (i == 2) { h4.z = hi; l4.z = lo2; }
          else { h4.w = hi; l4.w = lo2; }
        }
        *(ushort4*)&dh[off] = h4;
        *(ushort4*)&dl[off] = l4;
      }
    }
#pragma unroll
    for (int m = 32; m >= 1; m >>= 1) ss += __shfl_xor(ss, m, 64);
    if (lane == 0) atomicAdd(&sums[is_k ? 1 : 0], ss);
  } else {
    // normal: acc[mi][ni][i] = C[s=bm+wr+mi*16+quad*4+i][col=bn-2048... d]
#pragma unroll
    for (int ni = 0; ni < 4; ni++) {
      const int col = (bn - 2048) + wc + ni * 16 + lm;
      const int d = col & 63, hh = col >> 6;
#pragma unroll
      for (int mi = 0; mi < 4; mi++) {
        const int s0 = bm + wr + mi * 16 + quad * 4;
        const int b = s0 >> 10, sl = s0 & 1023, st = sl >> 6;
        const int sh = (sl & 63) >> 5, cc = (sl & 31) >> 3, eo = sl & 7;
        const size_t off = ((size_t)((b * 16 + hh) * 16 + st)) * 4096 +
                           sh * 2048 + d * 32 + ((cc ^ ((d >> 1) & 3)) * 8) + eo;
        ushort4 v4;
        v4.x = f2bf(acc[mi][ni][0]);
        v4.y = f2bf(acc[mi][ni][1]);
        v4.z = f2bf(acc[mi][ni][2]);
        v4.w = f2bf(acc[mi][ni][3]);
        *(ushort4*)&vT[off] = v4;
      }
    }
  }
}

// ============ fused attention (128 q rows/block, image k/v, z->images) ======
__global__ __launch_bounds__(256) void attn_kernel(
    const u16* __restrict__ qh, const u16* __restrict__ ql,
    const u16* __restrict__ kh, const u16* __restrict__ kl,
    const u16* __restrict__ vT, const float* __restrict__ sums,
    u16* __restrict__ z) {
  __shared__ u16 khs[4096], kls[4096], vts[4096];
  __shared__ u16 pb[4][2][1024];
  __shared__ float rsw[4][32];
  const int tid = threadIdx.x, wv = tid >> 6, lane = tid & 63;
  const int lm = lane & 15, quad = lane >> 4;
  const int fq = (quad ^ ((lm >> 1) & 3)) * 8;
  const int qt8 = blockIdx.x, hh = blockIdx.y, b = blockIdx.z;
  const float inv_rq = 1.f / (sqrtf(sums[0] * (1.f / 4194304.f)) + 1e-6f);
  const float inv_rk = 1.f / (sqrtf(sums[1] * (1.f / 4194304.f)) + 1e-6f);
  const float cs = inv_rq * inv_rk;
  const size_t hb = ((size_t)(b * 16 + hh)) * 65536;  // 16 stiles * 4096

  bf16x8 aH[2][2], aL[2][2];
#pragma unroll
  for (int qs = 0; qs < 2; qs++) {
    const int soff = wv * 32 + qs * 16;
    const size_t qb = hb + (size_t)(qt8 * 2 + (soff >> 6)) * 4096 +
                      (size_t)((soff & 63) + lm) * 32 + fq;
    aH[qs][0] = *(const bf16x8*)&qh[qb];
    aH[qs][1] = *(const bf16x8*)&qh[qb + 2048];
    aL[qs][0] = *(const bf16x8*)&ql[qb];
    aL[qs][1] = *(const bf16x8*)&ql[qb + 2048];
  }
  const f32x4 zz = {0.f, 0.f, 0.f, 0.f};
  f32x4 zac[2][4];
#pragma unroll
  for (int qs = 0; qs < 2; qs++)
#pragma unroll
    for (int dt = 0; dt < 4; dt++) zac[qs][dt] = zz;
  float rs[2][4] = {{0.f, 0.f, 0.f, 0.f}, {0.f, 0.f, 0.f, 0.f}};

  for (int it = 0; it < 16; it++) {
    __syncthreads();
    const u16* ks = kh + hb + it * 4096;
    const u16* ls = kl + hb + it * 4096;
    const u16* vs = vT + hb + it * 4096;
#pragma unroll
    for (int j = 0; j < 2; j++) {
      const int dof = (wv * 2 + j) * 512;
      gl_lds16(ks + dof + lane * 8, (char*)khs + dof * 2);
      gl_lds16(ls + dof + lane * 8, (char*)kls + dof * 2);
      gl_lds16(vs + dof + lane * 8, (char*)vts + dof * 2);
    }
    __syncthreads();
    f32x4 c[2][4];
#pragma unroll
    for (int qs = 0; qs < 2; qs++)
#pragma unroll
      for (int nt = 0; nt < 4; nt++) c[qs][nt] = zz;
#pragma unroll
    for (int nt = 0; nt < 4; nt++) {
      const int ro = (nt * 16 + lm) * 32 + fq;
      const bf16x8 bH0 = *(const bf16x8*)&khs[ro];
      const bf16x8 bH1 = *(const bf16x8*)&khs[2048 + ro];
      const bf16x8 bL0 = *(const bf16x8*)&kls[ro];
      const bf16x8 bL1 = *(const bf16x8*)&kls[2048 + ro];
#pragma unroll
      for (int qs = 0; qs < 2; qs++) {
        f32x4 cc = c[qs][nt];
        cc = __builtin_amdgcn_mfma_f32_16x16x32_bf16(aH[qs][0], bH0, cc, 0, 0, 0);
        cc = __builtin_amdgcn_mfma_f32_16x16x32_bf16(aH[qs][1], bH1, cc, 0, 0, 0);
        cc = __builtin_amdgcn_mfma_f32_16x16x32_bf16(aL[qs][0], bH0, cc, 0, 0, 0);
        cc = __builtin_amdgcn_mfma_f32_16x16x32_bf16(aL[qs][1], bH1, cc, 0, 0, 0);
        cc = __builtin_amdgcn_mfma_f32_16x16x32_bf16(aH[qs][0], bL0, cc, 0, 0, 0);
        cc = __builtin_amdgcn_mfma_f32_16x16x32_bf16(aH[qs][1], bL1, cc, 0, 0, 0);
        c[qs][nt] = cc;
      }
    }
#pragma unroll
    for (int qs = 0; qs < 2; qs++) {
      u16* pbw = pb[wv][qs];
#pragma unroll
      for (int nt = 0; nt < 4; nt++) {
        const int lchunk = nt * 2 + (lm >> 3);
#pragma unroll
        for (int i = 0; i < 4; i++) {
          const int row = quad * 4 + i;
          const float p = __expf(c[qs][nt][i] * cs - 60.f);
          rs[qs][i] += p;
          pbw[row * 64 + ((lchunk ^ (row & 7)) * 8) + (lm & 7)] = f2bf(p);
        }
      }
    }
#pragma unroll
    for (int ch = 0; ch < 2; ch++) {
      bf16x8 bv[4];
#pragma unroll
      for (int dt = 0; dt < 4; dt++)
        bv[dt] = *(const bf16x8*)&vts[ch * 2048 + (dt * 16 + lm) * 32 + fq];
#pragma unroll
      for (int qs = 0; qs < 2; qs++) {
        const bf16x8 ap = *(const bf16x8*)&pb[wv][qs]
            [lm * 64 + (((ch * 4 + quad) ^ (lm & 7)) * 8)];
#pragma unroll
        for (int dt = 0; dt < 4; dt++)
          zac[qs][dt] = __builtin_amdgcn_mfma_f32_16x16x32_bf16(
              bv[dt], ap, zac[qs][dt], 0, 0, 0);
      }
    }
  }
#pragma unroll
  for (int m = 1; m < 16; m <<= 1)
#pragma unroll
    for (int qs = 0; qs < 2; qs++)
#pragma unroll
      for (int i = 0; i < 4; i++) rs[qs][i] += __shfl_xor(rs[qs][i], m, 64);
  if (lm == 0)
#pragma unroll
    for (int qs = 0; qs < 2; qs++)
#pragma unroll
      for (int i = 0; i < 4; i++) rsw[wv][qs * 16 + quad * 4 + i] = rs[qs][i];
  __syncthreads();
  const int slab = b * 8 + qt8;
#pragma unroll
  for (int qs = 0; qs < 2; qs++) {
    const float inv = 1.f / rsw[wv][qs * 16 + lm];
    const int r = wv * 32 + qs * 16 + lm;
#pragma unroll
    for (int dt = 0; dt < 4; dt++) {
      const int kstep = hh * 2 + (dt >> 1);
      const int d0 = dt * 16 + quad * 4;
      const int cc = (d0 & 31) >> 3, eo = d0 & 7;
      const size_t off = ((size_t)(slab * 32 + kstep)) * 4096 + r * 32 +
                         ((cc ^ ((r >> 1) & 3)) * 8) + eo;
      ushort4 o;
      o.x = f2bf(zac[qs][dt][0] * inv);
      o.y = f2bf(zac[qs][dt][1] * inv);
      o.z = f2bf(zac[qs][dt][2] * inv);
      o.w = f2bf(zac[qs][dt][3] * inv);
      *(ushort4*)&z[off] = o;
    }
  }
}

// ============ output projection (image operands, swapped orientation) =======
__global__ __launch_bounds__(256) void gemm_o_kernel(const u16* __restrict__ Wop,
                                                     const u16* __restrict__ zp,
                                                     float* __restrict__ out) {
  __shared__ u16 As[8192], Bs[8192];
  const int tid = threadIdx.x, wv = tid >> 6, lane = tid & 63;
  const int lm = lane & 15, quad = lane >> 4;
  const int wr = (wv >> 1) * 64, wc = (wv & 1) * 64;
  const int fq = (quad ^ ((lm >> 1) & 3)) * 8;
  const u16* Ag = Wop + (size_t)blockIdx.x * 131072;
  const u16* Bg = zp + (size_t)blockIdx.y * 131072;
  const f32x4 z4 = {0.f, 0.f, 0.f, 0.f};
  f32x4 acc[4][4];
#pragma unroll
  for (int i = 0; i < 4; i++)
#pragma unroll
    for (int j = 0; j < 4; j++) acc[i][j] = z4;
  for (int t = 0; t < 16; t++) {
    __syncthreads();
    const size_t tb = (size_t)t * 8192;
#pragma unroll
    for (int j = 0; j < 4; j++) {
      const int dof = (wv * 4 + j) * 512;
      gl_lds16(Ag + tb + dof + lane * 8, (char*)As + dof * 2);
      gl_lds16(Bg + tb + dof + lane * 8, (char*)Bs + dof * 2);
    }
    __syncthreads();
#pragma unroll
    for (int j = 0; j < 2; j++) {
      const int hb = j * 4096;
      bf16x8 af[4];
#pragma unroll
      for (int mi = 0; mi < 4; mi++)
        af[mi] = *(const bf16x8*)&As[hb + (wr + mi * 16 + lm) * 32 + fq];
#pragma unroll
      for (int ni = 0; ni < 4; ni++) {
        const bf16x8 bf = *(const bf16x8*)&Bs[hb + (wc + ni * 16 + lm) * 32 + fq];
#pragma unroll
        for (int mi = 0; mi < 4; mi++)
          acc[mi][ni] = __builtin_amdgcn_mfma_f32_16x16x32_bf16(
              af[mi], bf, acc[mi][ni], 0, 0, 0);
      }
    }
  }
#pragma unroll
  for (int mi = 0; mi < 4; mi++) {
    const int col0 = blockIdx.x * 128 + wr + mi * 16 + quad * 4;
#pragma unroll
    for (int ni = 0; ni < 4; ni++) {
      const int s = blockIdx.y * 128 + wc + ni * 16 + lm;
      const float4 o = {acc[mi][ni][0], acc[mi][ni][1], acc[mi][ni][2],
                        acc[mi][ni][3]};
      *(float4*)&out[(size_t)s * 1024 + col0] = o;
    }
  }
}

extern "C" void kernel_launch(void* const* d_in, const int* in_sizes, int n_in,
                              void* d_out, int out_size, void* d_ws,
                              size_t ws_size, hipStream_t stream) {
  (void)in_sizes; (void)n_in; (void)out_size; (void)ws_size;
  const float* x = (const float*)d_in[0];
  const float* Wqkv = (const float*)d_in[1];
  const float* Wo = (const float*)d_in[2];
  const float* scale_q = (const float*)d_in[3];
  const float* scale_k = (const float*)d_in[4];
  float* out = (float*)d_out;

  // workspace (~60.8 MB)
  char* ws = (char*)d_ws;
  u16* qh = (u16*)(ws + 0);          // q hi images [b][h][stile][dhalf][2048]
  u16* ql = (u16*)(ws + 8388608);
  u16* kh = (u16*)(ws + 16777216);   // k (scaled) hi/lo images
  u16* kl = (u16*)(ws + 25165824);
  u16* Xp = (u16*)(ws + 33554432);   // X' images [32][32][4096]
  u16* vT = (u16*)(ws + 41943040);   // v images [b][h][stile][shalf][d][32]
  u16* Whp = (u16*)(ws + 50331648);  // Wqkv'^T hi images [24][32][4096]
  u16* Wlp = (u16*)(ws + 56623104);  // lo images [16][32][4096]
  u16* zp = Xp;                      // alias: X' dead after gemm_qkv
  u16* Wop = Whp;                    // alias: Whp dead after gemm_qkv
  float* sums = (float*)(ws + 60817408);

  conv_x_kernel<<<2048, 256, 0, stream>>>(x, Xp);
  conv_w_kernel<<<dim3(24, 16), 256, 0, stream>>>(Wqkv, 3072, Whp, Wlp, 16);
  hipMemsetAsync(sums, 0, 2 * sizeof(float), stream);
  gemm_qkv_kernel<<<dim3(24, 32), 256, 0, stream>>>(
      Xp, Whp, Wlp, qh, ql, kh, kl, vT, scale_q, scale_k, sums);
  conv_w_kernel<<<dim3(8, 16), 256, 0, stream>>>(Wo, 1024, Wop, nullptr, 0);
  attn_kernel<<<dim3(8, 16, 4), 256, 0, stream>>>(qh, ql, kh, kl, vT, sums, zp);
  gemm_o_kernel<<<dim3(8, 32), 256, 0, stream>>>(Wop, zp, out);
}

// Round 5
// 223.684 us; speedup vs baseline: 3.5984x; 1.1363x over previous
//
#include <hip/hip_runtime.h>

typedef float f32x4 __attribute__((ext_vector_type(4)));
typedef short bf16x8 __attribute__((ext_vector_type(8)));
typedef unsigned short u16;

__device__ __forceinline__ u16 f2bf(float f) {
  unsigned int u = __float_as_uint(f);
  u = u + 0x7fffu + ((u >> 16) & 1u);  // round-to-nearest-even
  return (u16)(u >> 16);
}
__device__ __forceinline__ float bf2f(u16 h) {
  return __uint_as_float(((unsigned int)h) << 16);
}

// Image unit = 8KB: [128 rows][32 k] bf16, chunk swizzle c' = c ^ ((r>>1)&3).
// Frag read offset within image: r*32 + ((quad ^ ((lm>>1)&3))*8) — 0-conflict.

// ============ conv_x: x (4096x1024 f32) -> X' images (32 slabs x 32 ksteps)
__global__ __launch_bounds__(256) void conv_x_kernel(const float* __restrict__ x,
                                                     u16* __restrict__ Xp) {
  const int g = blockIdx.x * 256 + threadIdx.x;
  const int o = g * 8;
  const int slab = o >> 17;
  const int rem = o & 131071;
  const int kstep = rem >> 12;
  const int rem2 = rem & 4095;
  const int r = rem2 >> 5;
  const int cp = (rem2 & 31) >> 3;
  const int c = cp ^ ((r >> 1) & 3);
  const int s = slab * 128 + r;
  const int k = kstep * 32 + c * 8;
  const float4 v0 = *(const float4*)&x[(size_t)s * 1024 + k];
  const float4 v1 = *(const float4*)&x[(size_t)s * 1024 + k + 4];
  ushort4 a, b;
  a.x = f2bf(v0.x); a.y = f2bf(v0.y); a.z = f2bf(v0.z); a.w = f2bf(v0.w);
  b.x = f2bf(v1.x); b.y = f2bf(v1.y); b.z = f2bf(v1.z); b.w = f2bf(v1.w);
  *(ushort4*)&Xp[o] = a;
  *(ushort4*)&Xp[o + 4] = b;
}

// ============ conv_w: W (1024 x ncols f32) -> W'^T images
__global__ __launch_bounds__(256) void conv_w_kernel(
    const float* __restrict__ src, int ncols, u16* __restrict__ dstHi,
    u16* __restrict__ dstLo, int lo_slabs) {
  __shared__ float tl[64][132];
  const int t = threadIdx.x;
  const int slab = blockIdx.x, kg = blockIdx.y;
  const int n0 = slab * 128, k0 = kg * 64;
#pragma unroll
  for (int i = 0; i < 8; i++) {
    const int fidx = i * 256 + t;
    const int r = fidx >> 5, c4 = (fidx & 31) * 4;
    *(float4*)&tl[r][c4] = *(const float4*)&src[(size_t)(k0 + r) * ncols + n0 + c4];
  }
  __syncthreads();
  const bool lo = slab < lo_slabs;
  const size_t base = (size_t)slab * 131072 + (size_t)(kg * 2) * 4096;
#pragma unroll
  for (int i = 0; i < 4; i++) {
    const int g = i * 256 + t;
    const int img = g >> 9, ci = g & 511;
    const int r = ci >> 2, cp = ci & 3;
    const int c = cp ^ ((r >> 1) & 3);
    const int klc = img * 32 + c * 8;
    ushort4 h0, h1, l0, l1;
    float v[8];
#pragma unroll
    for (int e = 0; e < 8; e++) v[e] = tl[klc + e][r];
    h0.x = f2bf(v[0]); h0.y = f2bf(v[1]); h0.z = f2bf(v[2]); h0.w = f2bf(v[3]);
    h1.x = f2bf(v[4]); h1.y = f2bf(v[5]); h1.z = f2bf(v[6]); h1.w = f2bf(v[7]);
    *(ushort4*)&dstHi[base + g * 8] = h0;
    *(ushort4*)&dstHi[base + g * 8 + 4] = h1;
    if (lo) {
      l0.x = f2bf(v[0] - bf2f(h0.x)); l0.y = f2bf(v[1] - bf2f(h0.y));
      l0.z = f2bf(v[2] - bf2f(h0.z)); l0.w = f2bf(v[3] - bf2f(h0.w));
      l1.x = f2bf(v[4] - bf2f(h1.x)); l1.y = f2bf(v[5] - bf2f(h1.y));
      l1.z = f2bf(v[6] - bf2f(h1.z)); l1.w = f2bf(v[7] - bf2f(h1.w));
      *(ushort4*)&dstLo[base + g * 8] = l0;
      *(ushort4*)&dstLo[base + g * 8 + 4] = l1;
    }
  }
}

// ============ fused qkv GEMM — register-prefetch dbuf pipeline ============
// Per t (BK=32): compute image t from LDS[cur]; ds_write image t+1 (vmcnt wait
// lands AFTER compute); buffer_load image t+2 into VGPRs. 1 barrier/iter.
__global__ __launch_bounds__(256) void gemm_qkv_kernel(
    const u16* __restrict__ Xp, const u16* __restrict__ Whp,
    const u16* __restrict__ Wlp, u16* __restrict__ qh, u16* __restrict__ ql,
    u16* __restrict__ kh, u16* __restrict__ kl, u16* __restrict__ vT,
    const float* __restrict__ scale_q, const float* __restrict__ scale_k,
    float* __restrict__ sums) {
  __shared__ u16 S[2][3][4096];  // [dbuf][X,Wh,Wl] 48KB
  const int tid = threadIdx.x, wv = tid >> 6, lane = tid & 63;
  const int lm = lane & 15, quad = lane >> 4;
  const int bnS = blockIdx.x, bmS = blockIdx.y;
  const bool is_v = (bnS >= 16);
  const int wr = (wv >> 1) * 64, wc = (wv & 1) * 64;
  const int fq = (quad ^ ((lm >> 1) & 3)) * 8;
  const u16* Xg = Xp + (size_t)bmS * 131072;
  const u16* Wg = Whp + (size_t)bnS * 131072;
  const u16* Lg = Wlp + (size_t)bnS * 131072;
  const int c0 = tid * 8, c1 = 2048 + tid * 8;  // elem offsets (16B/lane)
  const f32x4 z4 = {0.f, 0.f, 0.f, 0.f};
  f32x4 acc[4][4];
#pragma unroll
  for (int i = 0; i < 4; i++)
#pragma unroll
    for (int j = 0; j < 4; j++) acc[i][j] = z4;

  uint4 rx0, rx1, rw0, rw1, rl0, rl1;
#define LOADT(t)                                            \
  do {                                                      \
    const int tb_ = (t)*4096;                               \
    rx0 = *(const uint4*)(Xg + tb_ + c0);                   \
    rx1 = *(const uint4*)(Xg + tb_ + c1);                   \
    rw0 = *(const uint4*)(Wg + tb_ + c0);                   \
    rw1 = *(const uint4*)(Wg + tb_ + c1);                   \
    if (!is_v) {                                            \
      rl0 = *(const uint4*)(Lg + tb_ + c0);                 \
      rl1 = *(const uint4*)(Lg + tb_ + c1);                 \
    }                                                       \
  } while (0)
#define STORET(buf)                                         \
  do {                                                      \
    *(uint4*)(&S[buf][0][c0]) = rx0;                        \
    *(uint4*)(&S[buf][0][c1]) = rx1;                        \
    *(uint4*)(&S[buf][1][c0]) = rw0;                        \
    *(uint4*)(&S[buf][1][c1]) = rw1;                        \
    if (!is_v) {                                            \
      *(uint4*)(&S[buf][2][c0]) = rl0;                      \
      *(uint4*)(&S[buf][2][c1]) = rl1;                      \
    }                                                       \
  } while (0)

  LOADT(0);
  STORET(0);
  LOADT(1);
  for (int t = 0; t < 32; t++) {
    const int cur = t & 1;
    __syncthreads();
    const u16* Sx = S[cur][0];
    const u16* Sw = S[cur][1];
    const u16* Sl = S[cur][2];
    if (!is_v) {
      bf16x8 wh[4], wl[4];
#pragma unroll
      for (int mi = 0; mi < 4; mi++) {
        wh[mi] = *(const bf16x8*)&Sw[(wr + mi * 16 + lm) * 32 + fq];
        wl[mi] = *(const bf16x8*)&Sl[(wr + mi * 16 + lm) * 32 + fq];
      }
#pragma unroll
      for (int ni = 0; ni < 4; ni++) {
        const bf16x8 xh = *(const bf16x8*)&Sx[(wc + ni * 16 + lm) * 32 + fq];
#pragma unroll
        for (int mi = 0; mi < 4; mi++) {
          acc[mi][ni] = __builtin_amdgcn_mfma_f32_16x16x32_bf16(
              wh[mi], xh, acc[mi][ni], 0, 0, 0);
          acc[mi][ni] = __builtin_amdgcn_mfma_f32_16x16x32_bf16(
              wl[mi], xh, acc[mi][ni], 0, 0, 0);
        }
      }
    } else {
      bf16x8 xf[4];
#pragma unroll
      for (int mi = 0; mi < 4; mi++)
        xf[mi] = *(const bf16x8*)&Sx[(wr + mi * 16 + lm) * 32 + fq];
#pragma unroll
      for (int ni = 0; ni < 4; ni++) {
        const bf16x8 wf = *(const bf16x8*)&Sw[(wc + ni * 16 + lm) * 32 + fq];
#pragma unroll
        for (int mi = 0; mi < 4; mi++)
          acc[mi][ni] = __builtin_amdgcn_mfma_f32_16x16x32_bf16(
              xf[mi], wf, acc[mi][ni], 0, 0, 0);
      }
    }
    if (t < 31) STORET(cur ^ 1);
    if (t < 30) LOADT(t + 2);
  }
#undef LOADT
#undef STORET

  const int bn = bnS * 128, bm = bmS * 128;
  if (!is_v) {
    const bool is_k = (bnS >= 8);
    u16* dh = is_k ? kh : qh;
    u16* dl = is_k ? kl : ql;
    float ss = 0.f;
#pragma unroll
    for (int mi = 0; mi < 4; mi++) {
      const int col0 = bn + wr + mi * 16 + quad * 4;
      const int hh = (col0 >> 6) & 15, d0 = col0 & 63;
      const int dhi = d0 >> 5, cc = (d0 & 31) >> 3, eo = d0 & 7;
      float sc[4] = {1.f, 1.f, 1.f, 1.f};
      if (is_k) {
        const float4 sq = *(const float4*)&scale_q[d0];
        const float4 sk = *(const float4*)&scale_k[d0];
        sc[0] = sq.x * sk.x; sc[1] = sq.y * sk.y;
        sc[2] = sq.z * sk.z; sc[3] = sq.w * sk.w;
      }
#pragma unroll
      for (int ni = 0; ni < 4; ni++) {
        const int s = bm + wc + ni * 16 + lm;
        const int b = s >> 10, sl = s & 1023, st = sl >> 6, r = sl & 63;
        const size_t off = ((size_t)((b * 16 + hh) * 16 + st)) * 4096 +
                           dhi * 2048 + r * 32 + ((cc ^ ((r >> 1) & 3)) * 8) + eo;
        ushort4 h4, l4;
#pragma unroll
        for (int i = 0; i < 4; i++) {
          const float a = acc[mi][ni][i];
          ss += a * a;
          const float v = a * sc[i];
          const u16 hi = f2bf(v);
          const u16 lo2 = f2bf(v - bf2f(hi));
          if (i == 0) { h4.x = hi; l4.x = lo2; }
          else if (i == 1) { h4.y = hi; l4.y = lo2; }
          else if (i == 2) { h4.z = hi; l4.z = lo2; }
          else { h4.w = hi; l4.w = lo2; }
        }
        *(ushort4*)&dh[off] = h4;
        *(ushort4*)&dl[off] = l4;
      }
    }
#pragma unroll
    for (int m = 32; m >= 1; m >>= 1) ss += __shfl_xor(ss, m, 64);
    if (lane == 0) atomicAdd(&sums[is_k ? 1 : 0], ss);
  } else {
#pragma unroll
    for (int ni = 0; ni < 4; ni++) {
      const int col = (bn - 2048) + wc + ni * 16 + lm;
      const int d = col & 63, hh = col >> 6;
#pragma unroll
      for (int mi = 0; mi < 4; mi++) {
        const int s0 = bm + wr + mi * 16 + quad * 4;
        const int b = s0 >> 10, sl = s0 & 1023, st = sl >> 6;
        const int sh = (sl & 63) >> 5, cc = (sl & 31) >> 3, eo = sl & 7;
        const size_t off = ((size_t)((b * 16 + hh) * 16 + st)) * 4096 +
                           sh * 2048 + d * 32 + ((cc ^ ((d >> 1) & 3)) * 8) + eo;
        ushort4 v4;
        v4.x = f2bf(acc[mi][ni][0]);
        v4.y = f2bf(acc[mi][ni][1]);
        v4.z = f2bf(acc[mi][ni][2]);
        v4.w = f2bf(acc[mi][ni][3]);
        *(ushort4*)&vT[off] = v4;
      }
    }
  }
}

// ============ fused attention — same dbuf pipeline for k/l/v staging =======
__global__ __launch_bounds__(256) void attn_kernel(
    const u16* __restrict__ qh, const u16* __restrict__ ql,
    const u16* __restrict__ kh, const u16* __restrict__ kl,
    const u16* __restrict__ vT, const float* __restrict__ sums,
    u16* __restrict__ z) {
  __shared__ u16 S[2][3][4096];  // [dbuf][kh,kl,v] 48KB
  __shared__ u16 pb[4][2][1024];
  __shared__ float rsw[4][32];
  const int tid = threadIdx.x, wv = tid >> 6, lane = tid & 63;
  const int lm = lane & 15, quad = lane >> 4;
  const int fq = (quad ^ ((lm >> 1) & 3)) * 8;
  const int qt8 = blockIdx.x, hh = blockIdx.y, b = blockIdx.z;
  const float inv_rq = 1.f / (sqrtf(sums[0] * (1.f / 4194304.f)) + 1e-6f);
  const float inv_rk = 1.f / (sqrtf(sums[1] * (1.f / 4194304.f)) + 1e-6f);
  const float cs = inv_rq * inv_rk;
  const size_t hb = ((size_t)(b * 16 + hh)) * 65536;
  const u16* Kg = kh + hb;
  const u16* Lg = kl + hb;
  const u16* Vg = vT + hb;
  const int c0 = tid * 8, c1 = 2048 + tid * 8;

  bf16x8 aH[2][2], aL[2][2];
#pragma unroll
  for (int qs = 0; qs < 2; qs++) {
    const int soff = wv * 32 + qs * 16;
    const size_t qb = hb + (size_t)(qt8 * 2 + (soff >> 6)) * 4096 +
                      (size_t)((soff & 63) + lm) * 32 + fq;
    aH[qs][0] = *(const bf16x8*)&qh[qb];
    aH[qs][1] = *(const bf16x8*)&qh[qb + 2048];
    aL[qs][0] = *(const bf16x8*)&ql[qb];
    aL[qs][1] = *(const bf16x8*)&ql[qb + 2048];
  }
  const f32x4 zz = {0.f, 0.f, 0.f, 0.f};
  f32x4 zac[2][4];
#pragma unroll
  for (int qs = 0; qs < 2; qs++)
#pragma unroll
    for (int dt = 0; dt < 4; dt++) zac[qs][dt] = zz;
  float rs[2][4] = {{0.f, 0.f, 0.f, 0.f}, {0.f, 0.f, 0.f, 0.f}};

  uint4 rk0, rk1, rl0, rl1, rv0, rv1;
#define LOADT(t)                                   \
  do {                                             \
    const int tb_ = (t)*4096;                      \
    rk0 = *(const uint4*)(Kg + tb_ + c0);          \
    rk1 = *(const uint4*)(Kg + tb_ + c1);          \
    rl0 = *(const uint4*)(Lg + tb_ + c0);          \
    rl1 = *(const uint4*)(Lg + tb_ + c1);          \
    rv0 = *(const uint4*)(Vg + tb_ + c0);          \
    rv1 = *(const uint4*)(Vg + tb_ + c1);          \
  } while (0)
#define STORET(buf)                                \
  do {                                             \
    *(uint4*)(&S[buf][0][c0]) = rk0;               \
    *(uint4*)(&S[buf][0][c1]) = rk1;               \
    *(uint4*)(&S[buf][1][c0]) = rl0;               \
    *(uint4*)(&S[buf][1][c1]) = rl1;               \
    *(uint4*)(&S[buf][2][c0]) = rv0;               \
    *(uint4*)(&S[buf][2][c1]) = rv1;               \
  } while (0)

  LOADT(0);
  STORET(0);
  LOADT(1);
  for (int it = 0; it < 16; it++) {
    const int cur = it & 1;
    __syncthreads();
    const u16* khs = S[cur][0];
    const u16* kls = S[cur][1];
    const u16* vts = S[cur][2];
    f32x4 c[2][4];
#pragma unroll
    for (int qs = 0; qs < 2; qs++)
#pragma unroll
      for (int nt = 0; nt < 4; nt++) c[qs][nt] = zz;
#pragma unroll
    for (int nt = 0; nt < 4; nt++) {
      const int ro = (nt * 16 + lm) * 32 + fq;
      const bf16x8 bH0 = *(const bf16x8*)&khs[ro];
      const bf16x8 bH1 = *(const bf16x8*)&khs[2048 + ro];
      const bf16x8 bL0 = *(const bf16x8*)&kls[ro];
      const bf16x8 bL1 = *(const bf16x8*)&kls[2048 + ro];
#pragma unroll
      for (int qs = 0; qs < 2; qs++) {
        f32x4 cc = c[qs][nt];
        cc = __builtin_amdgcn_mfma_f32_16x16x32_bf16(aH[qs][0], bH0, cc, 0, 0, 0);
        cc = __builtin_amdgcn_mfma_f32_16x16x32_bf16(aH[qs][1], bH1, cc, 0, 0, 0);
        cc = __builtin_amdgcn_mfma_f32_16x16x32_bf16(aL[qs][0], bH0, cc, 0, 0, 0);
        cc = __builtin_amdgcn_mfma_f32_16x16x32_bf16(aL[qs][1], bH1, cc, 0, 0, 0);
        cc = __builtin_amdgcn_mfma_f32_16x16x32_bf16(aH[qs][0], bL0, cc, 0, 0, 0);
        cc = __builtin_amdgcn_mfma_f32_16x16x32_bf16(aH[qs][1], bL1, cc, 0, 0, 0);
        c[qs][nt] = cc;
      }
    }
#pragma unroll
    for (int qs = 0; qs < 2; qs++) {
      u16* pbw = pb[wv][qs];
#pragma unroll
      for (int nt = 0; nt < 4; nt++) {
        const int lchunk = nt * 2 + (lm >> 3);
#pragma unroll
        for (int i = 0; i < 4; i++) {
          const int row = quad * 4 + i;
          const float p = __expf(c[qs][nt][i] * cs - 60.f);
          rs[qs][i] += p;
          pbw[row * 64 + ((lchunk ^ (row & 7)) * 8) + (lm & 7)] = f2bf(p);
        }
      }
    }
#pragma unroll
    for (int ch = 0; ch < 2; ch++) {
      bf16x8 bv[4];
#pragma unroll
      for (int dt = 0; dt < 4; dt++)
        bv[dt] = *(const bf16x8*)&vts[ch * 2048 + (dt * 16 + lm) * 32 + fq];
#pragma unroll
      for (int qs = 0; qs < 2; qs++) {
        const bf16x8 ap = *(const bf16x8*)&pb[wv][qs]
            [lm * 64 + (((ch * 4 + quad) ^ (lm & 7)) * 8)];
#pragma unroll
        for (int dt = 0; dt < 4; dt++)
          zac[qs][dt] = __builtin_amdgcn_mfma_f32_16x16x32_bf16(
              bv[dt], ap, zac[qs][dt], 0, 0, 0);
      }
    }
    if (it < 15) STORET(cur ^ 1);
    if (it < 14) LOADT(it + 2);
  }
#undef LOADT
#undef STORET
#pragma unroll
  for (int m = 1; m < 16; m <<= 1)
#pragma unroll
    for (int qs = 0; qs < 2; qs++)
#pragma unroll
      for (int i = 0; i < 4; i++) rs[qs][i] += __shfl_xor(rs[qs][i], m, 64);
  if (lm == 0)
#pragma unroll
    for (int qs = 0; qs < 2; qs++)
#pragma unroll
      for (int i = 0; i < 4; i++) rsw[wv][qs * 16 + quad * 4 + i] = rs[qs][i];
  __syncthreads();
  const int slab = b * 8 + qt8;
#pragma unroll
  for (int qs = 0; qs < 2; qs++) {
    const float inv = 1.f / rsw[wv][qs * 16 + lm];
    const int r = wv * 32 + qs * 16 + lm;
#pragma unroll
    for (int dt = 0; dt < 4; dt++) {
      const int kstep = hh * 2 + (dt >> 1);
      const int d0 = dt * 16 + quad * 4;
      const int cc = (d0 & 31) >> 3, eo = d0 & 7;
      const size_t off = ((size_t)(slab * 32 + kstep)) * 4096 + r * 32 +
                         ((cc ^ ((r >> 1) & 3)) * 8) + eo;
      ushort4 o;
      o.x = f2bf(zac[qs][dt][0] * inv);
      o.y = f2bf(zac[qs][dt][1] * inv);
      o.z = f2bf(zac[qs][dt][2] * inv);
      o.w = f2bf(zac[qs][dt][3] * inv);
      *(ushort4*)&z[off] = o;
    }
  }
}

// ============ output projection — dbuf pipeline ============
__global__ __launch_bounds__(256) void gemm_o_kernel(const u16* __restrict__ Wop,
                                                     const u16* __restrict__ zp,
                                                     float* __restrict__ out) {
  __shared__ u16 S[2][2][4096];  // 32KB
  const int tid = threadIdx.x, wv = tid >> 6, lane = tid & 63;
  const int lm = lane & 15, quad = lane >> 4;
  const int wr = (wv >> 1) * 64, wc = (wv & 1) * 64;
  const int fq = (quad ^ ((lm >> 1) & 3)) * 8;
  const u16* Ag = Wop + (size_t)blockIdx.x * 131072;
  const u16* Bg = zp + (size_t)blockIdx.y * 131072;
  const int c0 = tid * 8, c1 = 2048 + tid * 8;
  const f32x4 z4 = {0.f, 0.f, 0.f, 0.f};
  f32x4 acc[4][4];
#pragma unroll
  for (int i = 0; i < 4; i++)
#pragma unroll
    for (int j = 0; j < 4; j++) acc[i][j] = z4;

  uint4 ra0, ra1, rb0, rb1;
#define LOADT(t)                                   \
  do {                                             \
    const int tb_ = (t)*4096;                      \
    ra0 = *(const uint4*)(Ag + tb_ + c0);          \
    ra1 = *(const uint4*)(Ag + tb_ + c1);          \
    rb0 = *(const uint4*)(Bg + tb_ + c0);          \
    rb1 = *(const uint4*)(Bg + tb_ + c1);          \
  } while (0)
#define STORET(buf)                                \
  do {                                             \
    *(uint4*)(&S[buf][0][c0]) = ra0;               \
    *(uint4*)(&S[buf][0][c1]) = ra1;               \
    *(uint4*)(&S[buf][1][c0]) = rb0;               \
    *(uint4*)(&S[buf][1][c1]) = rb1;               \
  } while (0)

  LOADT(0);
  STORET(0);
  LOADT(1);
  for (int t = 0; t < 32; t++) {
    const int cur = t & 1;
    __syncthreads();
    const u16* As = S[cur][0];
    const u16* Bs = S[cur][1];
    bf16x8 af[4];
#pragma unroll
    for (int mi = 0; mi < 4; mi++)
      af[mi] = *(const bf16x8*)&As[(wr + mi * 16 + lm) * 32 + fq];
#pragma unroll
    for (int ni = 0; ni < 4; ni++) {
      const bf16x8 bf = *(const bf16x8*)&Bs[(wc + ni * 16 + lm) * 32 + fq];
#pragma unroll
      for (int mi = 0; mi < 4; mi++)
        acc[mi][ni] = __builtin_amdgcn_mfma_f32_16x16x32_bf16(
            af[mi], bf, acc[mi][ni], 0, 0, 0);
    }
    if (t < 31) STORET(cur ^ 1);
    if (t < 30) LOADT(t + 2);
  }
#undef LOADT
#undef STORET
#pragma unroll
  for (int mi = 0; mi < 4; mi++) {
    const int col0 = blockIdx.x * 128 + wr + mi * 16 + quad * 4;
#pragma unroll
    for (int ni = 0; ni < 4; ni++) {
      const int s = blockIdx.y * 128 + wc + ni * 16 + lm;
      const float4 o = {acc[mi][ni][0], acc[mi][ni][1], acc[mi][ni][2],
                        acc[mi][ni][3]};
      *(float4*)&out[(size_t)s * 1024 + col0] = o;
    }
  }
}

extern "C" void kernel_launch(void* const* d_in, const int* in_sizes, int n_in,
                              void* d_out, int out_size, void* d_ws,
                              size_t ws_size, hipStream_t stream) {
  (void)in_sizes; (void)n_in; (void)out_size; (void)ws_size;
  const float* x = (const float*)d_in[0];
  const float* Wqkv = (const float*)d_in[1];
  const float* Wo = (const float*)d_in[2];
  const float* scale_q = (const float*)d_in[3];
  const float* scale_k = (const float*)d_in[4];
  float* out = (float*)d_out;

  char* ws = (char*)d_ws;
  u16* qh = (u16*)(ws + 0);
  u16* ql = (u16*)(ws + 8388608);
  u16* kh = (u16*)(ws + 16777216);
  u16* kl = (u16*)(ws + 25165824);
  u16* Xp = (u16*)(ws + 33554432);
  u16* vT = (u16*)(ws + 41943040);
  u16* Whp = (u16*)(ws + 50331648);
  u16* Wlp = (u16*)(ws + 56623104);
  u16* zp = Xp;
  u16* Wop = Whp;
  float* sums = (float*)(ws + 60817408);

  conv_x_kernel<<<2048, 256, 0, stream>>>(x, Xp);
  conv_w_kernel<<<dim3(24, 16), 256, 0, stream>>>(Wqkv, 3072, Whp, Wlp, 16);
  hipMemsetAsync(sums, 0, 2 * sizeof(float), stream);
  gemm_qkv_kernel<<<dim3(24, 32), 256, 0, stream>>>(
      Xp, Whp, Wlp, qh, ql, kh, kl, vT, scale_q, scale_k, sums);
  conv_w_kernel<<<dim3(8, 16), 256, 0, stream>>>(Wo, 1024, Wop, nullptr, 0);
  attn_kernel<<<dim3(8, 16, 4), 256, 0, stream>>>(qh, ql, kh, kl, vT, sums, zp);
  gemm_o_kernel<<<dim3(8, 32), 256, 0, stream>>>(Wop, zp, out);
}

// Round 6
// 194.276 us; speedup vs baseline: 4.1431x; 1.1514x over previous
//
#include <hip/hip_runtime.h>

typedef float f32x4 __attribute__((ext_vector_type(4)));
typedef short bf16x8 __attribute__((ext_vector_type(8)));
typedef _Float16 f16x8 __attribute__((ext_vector_type(8)));
typedef unsigned short u16;

__device__ __forceinline__ u16 f2bf(float f) {
  unsigned int u = __float_as_uint(f);
  u = u + 0x7fffu + ((u >> 16) & 1u);  // RNE
  return (u16)(u >> 16);
}
__device__ __forceinline__ float bf2f(u16 h) {
  return __uint_as_float(((unsigned int)h) << 16);
}
__device__ __forceinline__ u16 f2h(float f) {
  _Float16 h = (_Float16)f;  // v_cvt_f16_f32, RNE
  union { _Float16 h; u16 u; } cv;
  cv.h = h;
  return cv.u;
}

typedef unsigned int as1_uint __attribute__((address_space(1)));
typedef unsigned int as3_uint __attribute__((address_space(3)));
// async global->LDS, 16B/lane; LDS dest = wave-uniform base + lane*16
__device__ __forceinline__ void gl_lds16(const void* g, void* l) {
  __builtin_amdgcn_global_load_lds((as1_uint*)g, (as3_uint*)l, 16, 0, 0);
}

// Image unit = 8KB: [128 rows][32 k] elems, chunk swizzle c' = c ^ ((r>>1)&3).
// Frag read offset in image: r*32 + ((quad ^ ((lm>>1)&3))*8) — 0-conflict.

// ============ conv_x: x f32 -> X' f16 images (32 slabs x 32 ksteps) ========
__global__ __launch_bounds__(256) void conv_x_kernel(const float* __restrict__ x,
                                                     u16* __restrict__ Xp) {
  const int g = blockIdx.x * 256 + threadIdx.x;
  const int o = g * 8;
  const int slab = o >> 17;
  const int rem = o & 131071;
  const int kstep = rem >> 12;
  const int rem2 = rem & 4095;
  const int r = rem2 >> 5;
  const int cp = (rem2 & 31) >> 3;
  const int c = cp ^ ((r >> 1) & 3);
  const int s = slab * 128 + r;
  const int k = kstep * 32 + c * 8;
  const float4 v0 = *(const float4*)&x[(size_t)s * 1024 + k];
  const float4 v1 = *(const float4*)&x[(size_t)s * 1024 + k + 4];
  ushort4 a, b;
  a.x = f2h(v0.x); a.y = f2h(v0.y); a.z = f2h(v0.z); a.w = f2h(v0.w);
  b.x = f2h(v1.x); b.y = f2h(v1.y); b.z = f2h(v1.z); b.w = f2h(v1.w);
  *(ushort4*)&Xp[o] = a;
  *(ushort4*)&Xp[o + 4] = b;
}

// ============ conv_w: W f32 (1024 x ncols) -> W'^T f16 images ==============
__global__ __launch_bounds__(256) void conv_w_kernel(
    const float* __restrict__ src, int ncols, u16* __restrict__ dst) {
  __shared__ float tl[64][132];
  const int t = threadIdx.x;
  const int slab = blockIdx.x, kg = blockIdx.y;
  const int n0 = slab * 128, k0 = kg * 64;
#pragma unroll
  for (int i = 0; i < 8; i++) {
    const int fidx = i * 256 + t;
    const int r = fidx >> 5, c4 = (fidx & 31) * 4;
    *(float4*)&tl[r][c4] = *(const float4*)&src[(size_t)(k0 + r) * ncols + n0 + c4];
  }
  __syncthreads();
  const size_t base = (size_t)slab * 131072 + (size_t)(kg * 2) * 4096;
#pragma unroll
  for (int i = 0; i < 4; i++) {
    const int g = i * 256 + t;
    const int img = g >> 9, ci = g & 511;
    const int r = ci >> 2, cp = ci & 3;
    const int c = cp ^ ((r >> 1) & 3);
    const int klc = img * 32 + c * 8;
    ushort4 h0, h1;
    float v[8];
#pragma unroll
    for (int e = 0; e < 8; e++) v[e] = tl[klc + e][r];
    h0.x = f2h(v[0]); h0.y = f2h(v[1]); h0.z = f2h(v[2]); h0.w = f2h(v[3]);
    h1.x = f2h(v[4]); h1.y = f2h(v[5]); h1.z = f2h(v[6]); h1.w = f2h(v[7]);
    *(ushort4*)&dst[base + g * 8] = h0;
    *(ushort4*)&dst[base + g * 8 + 4] = h1;
  }
}

// ============ fused qkv GEMM — f16 single-term, async-LDS dbuf =============
// qk slabs (bnS<16): swapped orientation (A=W rows = output dims).
// v slabs: normal orientation (A=X rows = s). Epilogues write attn images.
__global__ __launch_bounds__(256) void gemm_qkv_kernel(
    const u16* __restrict__ Xp, const u16* __restrict__ Wp,
    u16* __restrict__ qf, u16* __restrict__ kf, u16* __restrict__ vT,
    const float* __restrict__ scale_q, const float* __restrict__ scale_k,
    float* __restrict__ sums) {
  __shared__ u16 Xs0[4096], Ws0[4096], Xs1[4096], Ws1[4096];  // 32 KB
  const int tid = threadIdx.x, wv = tid >> 6, lane = tid & 63;
  const int lm = lane & 15, quad = lane >> 4;
  const int bnS = blockIdx.x, bmS = blockIdx.y;
  const bool is_v = (bnS >= 16);
  const int wr = (wv >> 1) * 64, wc = (wv & 1) * 64;
  const int fq = (quad ^ ((lm >> 1) & 3)) * 8;
  const u16* Xg = Xp + (size_t)bmS * 131072;
  const u16* Wg = Wp + (size_t)bnS * 131072;
  const int dof0 = (wv * 2) * 512, dof1 = (wv * 2 + 1) * 512;
  const f32x4 z4 = {0.f, 0.f, 0.f, 0.f};
  f32x4 acc[4][4];
#pragma unroll
  for (int i = 0; i < 4; i++)
#pragma unroll
    for (int j = 0; j < 4; j++) acc[i][j] = z4;

#define ISSUE(t, Xs, Ws)                                   \
  do {                                                     \
    const size_t tb_ = (size_t)(t) * 4096;                 \
    gl_lds16(Xg + tb_ + dof0 + lane * 8, &Xs[dof0]);       \
    gl_lds16(Xg + tb_ + dof1 + lane * 8, &Xs[dof1]);       \
    gl_lds16(Wg + tb_ + dof0 + lane * 8, &Ws[dof0]);       \
    gl_lds16(Wg + tb_ + dof1 + lane * 8, &Ws[dof1]);       \
  } while (0)

  // A-role (wr rows) / B-role (wc rows) pointers per variant
  const u16* A0 = is_v ? Xs0 : Ws0;
  const u16* B0 = is_v ? Ws0 : Xs0;
  const u16* A1 = is_v ? Xs1 : Ws1;
  const u16* B1 = is_v ? Ws1 : Xs1;

  ISSUE(0, Xs0, Ws0);
  for (int t = 0; t < 32; t += 2) {
    __syncthreads();  // drains async loads into buf0
    {
      f16x8 afr[4], bfr[4];
#pragma unroll
      for (int mi = 0; mi < 4; mi++)
        afr[mi] = *(const f16x8*)&A0[(wr + mi * 16 + lm) * 32 + fq];
#pragma unroll
      for (int ni = 0; ni < 4; ni++)
        bfr[ni] = *(const f16x8*)&B0[(wc + ni * 16 + lm) * 32 + fq];
      ISSUE(t + 1, Xs1, Ws1);  // in flight during MFMA + next barrier
#pragma unroll
      for (int mi = 0; mi < 4; mi++)
#pragma unroll
        for (int ni = 0; ni < 4; ni++)
          acc[mi][ni] = __builtin_amdgcn_mfma_f32_16x16x32_f16(
              afr[mi], bfr[ni], acc[mi][ni], 0, 0, 0);
    }
    __syncthreads();  // drains loads into buf1
    {
      f16x8 afr[4], bfr[4];
#pragma unroll
      for (int mi = 0; mi < 4; mi++)
        afr[mi] = *(const f16x8*)&A1[(wr + mi * 16 + lm) * 32 + fq];
#pragma unroll
      for (int ni = 0; ni < 4; ni++)
        bfr[ni] = *(const f16x8*)&B1[(wc + ni * 16 + lm) * 32 + fq];
      if (t + 2 < 32) ISSUE(t + 2, Xs0, Ws0);
#pragma unroll
      for (int mi = 0; mi < 4; mi++)
#pragma unroll
        for (int ni = 0; ni < 4; ni++)
          acc[mi][ni] = __builtin_amdgcn_mfma_f32_16x16x32_f16(
              afr[mi], bfr[ni], acc[mi][ni], 0, 0, 0);
    }
  }
#undef ISSUE

  const int bn = bnS * 128, bm = bmS * 128;
  if (!is_v) {
    // swapped: acc[mi][ni][i] = C[col=bn+wr+mi*16+quad*4+i][s=bm+wc+ni*16+lm]
    const bool is_k = (bnS >= 8);
    u16* dst = is_k ? kf : qf;
    float ss = 0.f;
#pragma unroll
    for (int mi = 0; mi < 4; mi++) {
      const int col0 = bn + wr + mi * 16 + quad * 4;
      const int hh = (col0 >> 6) & 15, d0 = col0 & 63;
      const int dhi = d0 >> 5, cc = (d0 & 31) >> 3, eo = d0 & 7;
      float sc[4] = {1.f, 1.f, 1.f, 1.f};
      if (is_k) {
        const float4 sq = *(const float4*)&scale_q[d0];
        const float4 sk = *(const float4*)&scale_k[d0];
        sc[0] = sq.x * sk.x; sc[1] = sq.y * sk.y;
        sc[2] = sq.z * sk.z; sc[3] = sq.w * sk.w;
      }
#pragma unroll
      for (int ni = 0; ni < 4; ni++) {
        const int s = bm + wc + ni * 16 + lm;
        const int b = s >> 10, sl = s & 1023, st = sl >> 6, r = sl & 63;
        const size_t off = ((size_t)((b * 16 + hh) * 16 + st)) * 4096 +
                           dhi * 2048 + r * 32 + ((cc ^ ((r >> 1) & 3)) * 8) + eo;
        ushort4 h4;
#pragma unroll
        for (int i = 0; i < 4; i++) {
          const float a = acc[mi][ni][i];
          ss += a * a;  // raw (pre-scale) for global RMS
          const u16 hv = f2h(a * sc[i]);
          if (i == 0) h4.x = hv;
          else if (i == 1) h4.y = hv;
          else if (i == 2) h4.z = hv;
          else h4.w = hv;
        }
        *(ushort4*)&dst[off] = h4;
      }
    }
#pragma unroll
    for (int m = 32; m >= 1; m >>= 1) ss += __shfl_xor(ss, m, 64);
    if (lane == 0) atomicAdd(&sums[is_k ? 1 : 0], ss);
  } else {
    // normal: acc[mi][ni][i] = C[s=bm+wr+mi*16+quad*4+i][d-col]; v stored bf16
#pragma unroll
    for (int ni = 0; ni < 4; ni++) {
      const int col = (bn - 2048) + wc + ni * 16 + lm;
      const int d = col & 63, hh = col >> 6;
#pragma unroll
      for (int mi = 0; mi < 4; mi++) {
        const int s0 = bm + wr + mi * 16 + quad * 4;
        const int b = s0 >> 10, sl = s0 & 1023, st = sl >> 6;
        const int sh = (sl & 63) >> 5, cc = (sl & 31) >> 3, eo = sl & 7;
        const size_t off = ((size_t)((b * 16 + hh) * 16 + st)) * 4096 +
                           sh * 2048 + d * 32 + ((cc ^ ((d >> 1) & 3)) * 8) + eo;
        ushort4 v4;
        v4.x = f2bf(acc[mi][ni][0]);
        v4.y = f2bf(acc[mi][ni][1]);
        v4.z = f2bf(acc[mi][ni][2]);
        v4.w = f2bf(acc[mi][ni][3]);
        *(ushort4*)&vT[off] = v4;
      }
    }
  }
}

// ============ fused attention — f16 QK (swapped), bf16 PV ============
// Swapped QK: A=k (rows=k-idx), B=q -> D[k=quad*4+i][q=lm]: p writes are
// k-contiguous b64; rowsum reduces over quad only (2 shuffles).
__global__ __launch_bounds__(256) void attn_kernel(
    const u16* __restrict__ qf, const u16* __restrict__ kf,
    const u16* __restrict__ vT, const float* __restrict__ sums,
    u16* __restrict__ z) {
  __shared__ u16 Ks0[4096], Vs0[4096], Ks1[4096], Vs1[4096];  // 32 KB
  __shared__ u16 pb[4][2][16][64];                            // 16 KB
  const int tid = threadIdx.x, wv = tid >> 6, lane = tid & 63;
  const int lm = lane & 15, quad = lane >> 4;
  const int fq = (quad ^ ((lm >> 1) & 3)) * 8;
  const int qt8 = blockIdx.x, hh = blockIdx.y, b = blockIdx.z;
  const float inv_rq = 1.f / (sqrtf(sums[0] * (1.f / 4194304.f)) + 1e-6f);
  const float inv_rk = 1.f / (sqrtf(sums[1] * (1.f / 4194304.f)) + 1e-6f);
  const float cs = inv_rq * inv_rk;
  const size_t hb = ((size_t)(b * 16 + hh)) * 65536;
  const u16* Kg = kf + hb;
  const u16* Vg = vT + hb;
  const int dof = wv * 1024;

  // q frags (B-operand role): B[n=lm][k=d], rows = wave's q set
  f16x8 aF[2][2];
#pragma unroll
  for (int qs = 0; qs < 2; qs++) {
    const int soff = wv * 32 + qs * 16;
    const size_t qb = hb + (size_t)(qt8 * 2 + (soff >> 6)) * 4096 +
                      (size_t)((soff & 63) + lm) * 32 + fq;
    aF[qs][0] = *(const f16x8*)&qf[qb];
    aF[qs][1] = *(const f16x8*)&qf[qb + 2048];
  }
  const f32x4 zz = {0.f, 0.f, 0.f, 0.f};
  f32x4 zac[2][4];
#pragma unroll
  for (int qs = 0; qs < 2; qs++)
#pragma unroll
    for (int dt = 0; dt < 4; dt++) zac[qs][dt] = zz;
  float rs[2] = {0.f, 0.f};

#define AISSUE(it, Ks, Vs)                                    \
  do {                                                        \
    const size_t tb_ = (size_t)(it) * 4096;                   \
    gl_lds16(Kg + tb_ + dof + lane * 8, &Ks[dof]);            \
    gl_lds16(Kg + tb_ + dof + 512 + lane * 8, &Ks[dof + 512]);\
    gl_lds16(Vg + tb_ + dof + lane * 8, &Vs[dof]);            \
    gl_lds16(Vg + tb_ + dof + 512 + lane * 8, &Vs[dof + 512]);\
  } while (0)

#define ATTN_BODY(it, Ks, Vs, Kn, Vn, do_issue)                               \
  do {                                                                        \
    /* pre-read all frags of this tile */                                     \
    f16x8 kf0[4], kf1[4];                                                     \
    bf16x8 bv[2][4];                                                          \
_Pragma("unroll")                                                             \
    for (int nt = 0; nt < 4; nt++) {                                          \
      const int ro = (nt * 16 + lm) * 32 + fq;                                \
      kf0[nt] = *(const f16x8*)&Ks[ro];                                       \
      kf1[nt] = *(const f16x8*)&Ks[2048 + ro];                                \
    }                                                                         \
_Pragma("unroll")                                                             \
    for (int ch = 0; ch < 2; ch++)                                            \
_Pragma("unroll")                                                             \
      for (int dt = 0; dt < 4; dt++)                                          \
        bv[ch][dt] = *(const bf16x8*)&Vs[ch * 2048 + (dt * 16 + lm) * 32 + fq];\
    if (do_issue) AISSUE((it) + 1, Kn, Vn);                                   \
    /* QK swapped + softmax numerator + p to LDS (b64, swizzled) */           \
_Pragma("unroll")                                                             \
    for (int qs = 0; qs < 2; qs++) {                                          \
_Pragma("unroll")                                                             \
      for (int nt = 0; nt < 4; nt++) {                                        \
        f32x4 c = zz;                                                         \
        c = __builtin_amdgcn_mfma_f32_16x16x32_f16(kf0[nt], aF[qs][0], c, 0, 0, 0);\
        c = __builtin_amdgcn_mfma_f32_16x16x32_f16(kf1[nt], aF[qs][1], c, 0, 0, 0);\
        const int k4 = nt * 4 + quad;                                         \
        const int sw = (k4 & 8) | ((k4 ^ lm) & 7);                            \
        ushort4 pw;                                                           \
        float p0 = __expf(c[0] * cs - 60.f);                                  \
        float p1 = __expf(c[1] * cs - 60.f);                                  \
        float p2 = __expf(c[2] * cs - 60.f);                                  \
        float p3 = __expf(c[3] * cs - 60.f);                                  \
        rs[qs] += (p0 + p1) + (p2 + p3);                                      \
        pw.x = f2bf(p0); pw.y = f2bf(p1); pw.z = f2bf(p2); pw.w = f2bf(p3);   \
        *(ushort4*)&pb[wv][qs][lm][sw * 4] = pw;                              \
      }                                                                       \
    }                                                                         \
    /* PV swapped: A=v rows=d, B=p rows=q (b64 pair reads, swizzled) */       \
_Pragma("unroll")                                                             \
    for (int ch = 0; ch < 2; ch++) {                                          \
_Pragma("unroll")                                                             \
      for (int qs = 0; qs < 2; qs++) {                                        \
        const int k4a = ch * 8 + quad * 2, k4b = k4a + 1;                     \
        const ushort4 lo4 =                                                   \
            *(const ushort4*)&pb[wv][qs][lm][((k4a & 8) | ((k4a ^ lm) & 7)) * 4];\
        const ushort4 hi4 =                                                   \
            *(const ushort4*)&pb[wv][qs][lm][((k4b & 8) | ((k4b ^ lm) & 7)) * 4];\
        bf16x8 ap;                                                            \
        ap[0] = (short)lo4.x; ap[1] = (short)lo4.y;                           \
        ap[2] = (short)lo4.z; ap[3] = (short)lo4.w;                           \
        ap[4] = (short)hi4.x; ap[5] = (short)hi4.y;                           \
        ap[6] = (short)hi4.z; ap[7] = (short)hi4.w;                           \
_Pragma("unroll")                                                             \
        for (int dt = 0; dt < 4; dt++)                                        \
          zac[qs][dt] = __builtin_amdgcn_mfma_f32_16x16x32_bf16(              \
              bv[ch][dt], ap, zac[qs][dt], 0, 0, 0);                          \
      }                                                                       \
    }                                                                         \
  } while (0)

  AISSUE(0, Ks0, Vs0);
  for (int it = 0; it < 16; it += 2) {
    __syncthreads();
    ATTN_BODY(it, Ks0, Vs0, Ks1, Vs1, true);
    __syncthreads();
    ATTN_BODY(it + 1, Ks1, Vs1, Ks0, Vs0, (it + 2 < 16));
  }
#undef AISSUE
#undef ATTN_BODY

  // rowsum for q=lm: reduce over quad groups only
#pragma unroll
  for (int qs = 0; qs < 2; qs++) {
    rs[qs] += __shfl_xor(rs[qs], 16, 64);
    rs[qs] += __shfl_xor(rs[qs], 32, 64);
  }
  const int slab = b * 8 + qt8;
#pragma unroll
  for (int qs = 0; qs < 2; qs++) {
    const float inv = 1.f / rs[qs];
    const int r = wv * 32 + qs * 16 + lm;
#pragma unroll
    for (int dt = 0; dt < 4; dt++) {
      const int kstep = hh * 2 + (dt >> 1);
      const int d0 = dt * 16 + quad * 4;
      const int cc = (d0 & 31) >> 3, eo = d0 & 7;
      const size_t off = ((size_t)(slab * 32 + kstep)) * 4096 + r * 32 +
                         ((cc ^ ((r >> 1) & 3)) * 8) + eo;
      ushort4 o;
      o.x = f2h(zac[qs][dt][0] * inv);
      o.y = f2h(zac[qs][dt][1] * inv);
      o.z = f2h(zac[qs][dt][2] * inv);
      o.w = f2h(zac[qs][dt][3] * inv);
      *(ushort4*)&z[off] = o;
    }
  }
}

// ============ output projection — f16, async-LDS dbuf, swapped =============
__global__ __launch_bounds__(256) void gemm_o_kernel(const u16* __restrict__ Wop,
                                                     const u16* __restrict__ zp,
                                                     float* __restrict__ out) {
  __shared__ u16 As0[4096], Bs0[4096], As1[4096], Bs1[4096];
  const int tid = threadIdx.x, wv = tid >> 6, lane = tid & 63;
  const int lm = lane & 15, quad = lane >> 4;
  const int wr = (wv >> 1) * 64, wc = (wv & 1) * 64;
  const int fq = (quad ^ ((lm >> 1) & 3)) * 8;
  const u16* Ag = Wop + (size_t)blockIdx.x * 131072;
  const u16* Bg = zp + (size_t)blockIdx.y * 131072;
  const int dof0 = (wv * 2) * 512, dof1 = (wv * 2 + 1) * 512;
  const f32x4 z4 = {0.f, 0.f, 0.f, 0.f};
  f32x4 acc[4][4];
#pragma unroll
  for (int i = 0; i < 4; i++)
#pragma unroll
    for (int j = 0; j < 4; j++) acc[i][j] = z4;

#define ISSUE(t, As, Bs)                                   \
  do {                                                     \
    const size_t tb_ = (size_t)(t) * 4096;                 \
    gl_lds16(Ag + tb_ + dof0 + lane * 8, &As[dof0]);       \
    gl_lds16(Ag + tb_ + dof1 + lane * 8, &As[dof1]);       \
    gl_lds16(Bg + tb_ + dof0 + lane * 8, &Bs[dof0]);       \
    gl_lds16(Bg + tb_ + dof1 + lane * 8, &Bs[dof1]);       \
  } while (0)
#define GBODY(As, Bs)                                                     \
  do {                                                                    \
    f16x8 afr[4], bfr[4];                                                 \
_Pragma("unroll")                                                         \
    for (int mi = 0; mi < 4; mi++)                                        \
      afr[mi] = *(const f16x8*)&As[(wr + mi * 16 + lm) * 32 + fq];        \
_Pragma("unroll")                                                         \
    for (int ni = 0; ni < 4; ni++)                                        \
      bfr[ni] = *(const f16x8*)&Bs[(wc + ni * 16 + lm) * 32 + fq];        \
    DO_ISSUE;                                                             \
_Pragma("unroll")                                                         \
    for (int mi = 0; mi < 4; mi++)                                        \
_Pragma("unroll")                                                         \
      for (int ni = 0; ni < 4; ni++)                                      \
        acc[mi][ni] = __builtin_amdgcn_mfma_f32_16x16x32_f16(             \
            afr[mi], bfr[ni], acc[mi][ni], 0, 0, 0);                      \
  } while (0)

  ISSUE(0, As0, Bs0);
  for (int t = 0; t < 32; t += 2) {
    __syncthreads();
#define DO_ISSUE ISSUE(t + 1, As1, Bs1)
    GBODY(As0, Bs0);
#undef DO_ISSUE
    __syncthreads();
#define DO_ISSUE if (t + 2 < 32) ISSUE(t + 2, As0, Bs0)
    GBODY(As1, Bs1);
#undef DO_ISSUE
  }
#undef ISSUE
#undef GBODY

#pragma unroll
  for (int mi = 0; mi < 4; mi++) {
    const int col0 = blockIdx.x * 128 + wr + mi * 16 + quad * 4;
#pragma unroll
    for (int ni = 0; ni < 4; ni++) {
      const int s = blockIdx.y * 128 + wc + ni * 16 + lm;
      const float4 o = {acc[mi][ni][0], acc[mi][ni][1], acc[mi][ni][2],
                        acc[mi][ni][3]};
      *(float4*)&out[(size_t)s * 1024 + col0] = o;
    }
  }
}

extern "C" void kernel_launch(void* const* d_in, const int* in_sizes, int n_in,
                              void* d_out, int out_size, void* d_ws,
                              size_t ws_size, hipStream_t stream) {
  (void)in_sizes; (void)n_in; (void)out_size; (void)ws_size;
  const float* x = (const float*)d_in[0];
  const float* Wqkv = (const float*)d_in[1];
  const float* Wo = (const float*)d_in[2];
  const float* scale_q = (const float*)d_in[3];
  const float* scale_k = (const float*)d_in[4];
  float* out = (float*)d_out;

  // workspace (~40 MB)
  char* ws = (char*)d_ws;
  u16* qf = (u16*)(ws + 0);          // q f16 images [b*16+h][st][dhi][64r][32d]
  u16* kf = (u16*)(ws + 8388608);    // k (scaled) f16 images
  u16* Xp = (u16*)(ws + 16777216);   // X' f16 images [32][32][4096]
  u16* vT = (u16*)(ws + 25165824);   // v bf16 images [b*16+h][st][sh][64d][32s]
  u16* Wp = (u16*)(ws + 33554432);   // Wqkv'^T f16 images [24][32][4096]
  u16* zp = Xp;                      // alias: X' dead after gemm_qkv
  u16* Wop = Wp;                     // alias: Wp dead after gemm_qkv
  float* sums = (float*)(ws + 39845888);

  conv_x_kernel<<<2048, 256, 0, stream>>>(x, Xp);
  conv_w_kernel<<<dim3(24, 16), 256, 0, stream>>>(Wqkv, 3072, Wp);
  hipMemsetAsync(sums, 0, 2 * sizeof(float), stream);
  gemm_qkv_kernel<<<dim3(24, 32), 256, 0, stream>>>(Xp, Wp, qf, kf, vT,
                                                    scale_q, scale_k, sums);
  conv_w_kernel<<<dim3(8, 16), 256, 0, stream>>>(Wo, 1024, Wop);
  attn_kernel<<<dim3(8, 16, 4), 256, 0, stream>>>(qf, kf, vT, sums, zp);
  gemm_o_kernel<<<dim3(8, 32), 256, 0, stream>>>(Wop, zp, out);
}